// Round 2
// baseline (1502.656 us; speedup 1.0000x reference)
//
#include <hip/hip_runtime.h>
#include <hip/hip_bf16.h>
#include <math.h>

#define TSEQ 2048
#define MROWS 4096   // B*T
#define NHID 1024

typedef float f32x4 __attribute__((ext_vector_type(4)));
typedef __bf16 bf16x8 __attribute__((ext_vector_type(8)));

static __device__ __forceinline__ unsigned short f2bf(float f) {
  unsigned u = __float_as_uint(f);
  u += 0x7fffu + ((u >> 16) & 1u);
  return (unsigned short)(u >> 16);
}

// ---------------- cast x (f32) -> bf16 ----------------
__global__ __launch_bounds__(256) void cast_x_kernel(const float* __restrict__ X,
                                                     unsigned short* __restrict__ Xb) {
  int i = (blockIdx.x * 256 + threadIdx.x) * 4;
  float4 v = *(const float4*)(X + i);
  ushort4 o;
  o.x = f2bf(v.x); o.y = f2bf(v.y); o.z = f2bf(v.z); o.w = f2bf(v.w);
  *(ushort4*)(Xb + i) = o;
}

// ------------- transpose 1024x1024 f32 (K,N) -> bf16 (N,K) -------------
__global__ __launch_bounds__(256) void transpose_w_kernel(const float* __restrict__ W,
                                                          unsigned short* __restrict__ Wt) {
  __shared__ float tile[32][33];
  int bx = blockIdx.x * 32;  // n block
  int by = blockIdx.y * 32;  // k block
  int tx = threadIdx.x, ty = threadIdx.y;
#pragma unroll
  for (int i = 0; i < 32; i += 8)
    tile[ty + i][tx] = W[(size_t)(by + ty + i) * NHID + bx + tx];
  __syncthreads();
#pragma unroll
  for (int i = 0; i < 32; i += 8)
    Wt[(size_t)(bx + ty + i) * NHID + by + tx] = f2bf(tile[tx][ty + i]);
}

// ------------- bf16 MFMA GEMM: C[M=4096][1024] = epi(A @ Bt^T) -------------
// A: bf16 [4096][1024] (K contiguous), Bt: bf16 [1024][1024] (N-major, K contiguous)
// EPI: 0 = identity (f32 out), 1 = elu(z)+1 (f32 out), 2 = z + bias[col] + res[row][col] (f32 out)
template <int EPI>
__global__ __launch_bounds__(256) void gemm128_kernel(const unsigned short* __restrict__ A,
                                                      const unsigned short* __restrict__ Bt,
                                                      float* __restrict__ C,
                                                      const float* __restrict__ bias,
                                                      const float* __restrict__ res) {
  __shared__ __align__(16) unsigned short As[128][32];
  __shared__ __align__(16) unsigned short Bs[128][32];
  const int tid = threadIdx.x;
  const int lane = tid & 63;
  const int wave = tid >> 6;
  const int wr = wave >> 1, wc = wave & 1;
  const int rowBase = blockIdx.y * 128;
  const int colBase = blockIdx.x * 128;

  // staging: 512 16B-chunks per tile, 2 per thread. chunk c -> (row=c>>2, kc=c&3)
  const int c0 = tid, c1 = tid + 256;
  const int r0 = c0 >> 2, kc0 = c0 & 3, sl0 = kc0 ^ ((r0 >> 1) & 3);
  const int r1 = c1 >> 2, kc1 = c1 & 3, sl1 = kc1 ^ ((r1 >> 1) & 3);

  const int kq = lane >> 4;   // k-slot 0..3
  const int r16 = lane & 15;

  f32x4 acc[4][4] = {};

  for (int k0 = 0; k0 < 1024; k0 += 32) {
    bf16x8 a0 = *(const bf16x8*)(A + (size_t)(rowBase + r0) * 1024 + k0 + kc0 * 8);
    bf16x8 a1 = *(const bf16x8*)(A + (size_t)(rowBase + r1) * 1024 + k0 + kc1 * 8);
    bf16x8 b0 = *(const bf16x8*)(Bt + (size_t)(colBase + r0) * 1024 + k0 + kc0 * 8);
    bf16x8 b1 = *(const bf16x8*)(Bt + (size_t)(colBase + r1) * 1024 + k0 + kc1 * 8);
    __syncthreads();  // previous iteration's frag reads done
    *(bf16x8*)&As[r0][sl0 * 8] = a0;
    *(bf16x8*)&As[r1][sl1 * 8] = a1;
    *(bf16x8*)&Bs[r0][sl0 * 8] = b0;
    *(bf16x8*)&Bs[r1][sl1 * 8] = b1;
    __syncthreads();
    bf16x8 af[4], bfr[4];
#pragma unroll
    for (int m = 0; m < 4; ++m) {
      int row = wr * 64 + m * 16 + r16;
      af[m] = *(const bf16x8*)&As[row][(kq ^ ((row >> 1) & 3)) * 8];
      int colr = wc * 64 + m * 16 + r16;
      bfr[m] = *(const bf16x8*)&Bs[colr][(kq ^ ((colr >> 1) & 3)) * 8];
    }
#pragma unroll
    for (int m = 0; m < 4; ++m)
#pragma unroll
      for (int n = 0; n < 4; ++n)
        acc[m][n] = __builtin_amdgcn_mfma_f32_16x16x32_bf16(af[m], bfr[n], acc[m][n], 0, 0, 0);
  }

  const int r4 = (lane >> 4) * 4;
#pragma unroll
  for (int m = 0; m < 4; ++m) {
#pragma unroll
    for (int n = 0; n < 4; ++n) {
      int col = colBase + wc * 64 + n * 16 + r16;
#pragma unroll
      for (int j = 0; j < 4; ++j) {
        int row = rowBase + wr * 64 + m * 16 + r4 + j;
        float v = acc[m][n][j];
        if (EPI == 1) v = (v > 0.f) ? (v + 1.f) : expf(v);
        if (EPI == 2) v += bias[col] + res[(size_t)row * 1024 + col];
        C[(size_t)row * 1024 + col] = v;
      }
    }
  }
}

// ------------- per-(b,t): decay r_eff and softmax mix weights -------------
__global__ __launch_bounds__(256) void small_rw_kernel(const float* __restrict__ x,
    const float* __restrict__ Wb, const float* __restrict__ bb,
    const float* __restrict__ Wm, const float* __restrict__ bm,
    const float* __restrict__ base_logit,
    float* __restrict__ R, float* __restrict__ Wsm) {
  int row = blockIdx.x;  // b*T + t
  __shared__ float xs[1024];
  __shared__ float outs[40];
  int tid = threadIdx.x;
  const float* xr = x + (size_t)row * 1024;
  for (int i = tid; i < 1024; i += 256) xs[i] = xr[i];
  __syncthreads();
  int wave = tid >> 6, lane = tid & 63;
  for (int o = wave; o < 40; o += 4) {
    float sum = 0.f;
    if (o < 8) {
      for (int i = lane; i < 1024; i += 64) sum += xs[i] * Wb[i * 8 + o];
    } else {
      int c = o - 8;
      for (int i = lane; i < 1024; i += 64) sum += xs[i] * Wm[i * 32 + c];
    }
#pragma unroll
    for (int off = 32; off > 0; off >>= 1) sum += __shfl_down(sum, off);
    if (lane == 0) outs[o] = sum;
  }
  __syncthreads();
  if (tid < 32) {
    int h = tid >> 2;
    float beta = 1.f / (1.f + expf(-(outs[h] + bb[h])));
    float br = 1.f / (1.f + expf(-base_logit[tid]));
    float r = fminf(fmaxf(beta * br, 0.f), 0.999995f);
    float mval = outs[8 + tid] + bm[tid];
    float mx = fmaxf(mval, __shfl_xor(mval, 1));
    mx = fmaxf(mx, __shfl_xor(mx, 2));
    float ex = expf(mval - mx);
    float ssum = ex + __shfl_xor(ex, 1);
    ssum += __shfl_xor(ssum, 2);
    R[(size_t)row * 32 + tid] = r;
    Wsm[(size_t)row * 32 + tid] = ex / ssum;
  }
}

// ------------- the recurrent scan -------------
// grid: 256 WGs = 16 (b,h) x 16 col-groups(8 cols). 256 threads = 4 kk x 8 row-parts x 8 cols.
// thread owns state rows rp*16..+15, one column, chain kk, in 16 f32 registers.
__global__ __launch_bounds__(256) void scan_kernel(const float* __restrict__ Q,
    const float* __restrict__ Kf, const float* __restrict__ V,
    const float* __restrict__ R, const float* __restrict__ Wsm,
    const float* __restrict__ mask, unsigned short* __restrict__ O) {
  __shared__ float po_lds[8][16][32];  // [e][j][kk*8+rp]
  int wg = blockIdx.x;
  int bh = wg >> 4, cg = wg & 15;
  int b = bh >> 3, h = bh & 7;
  int tid = threadIdx.x;
  int kk = tid >> 6;
  int rp = (tid >> 3) & 7;
  int e = tid & 7;
  int col = cg * 8 + e;

  float s[16];
#pragma unroll
  for (int i = 0; i < 16; ++i) s[i] = 0.f;

  const size_t base0 = (size_t)b * TSEQ * 1024 + (size_t)h * 128;
  const int rwbase0 = b * TSEQ * 32 + h * 4 + kk;

  for (int blk = 0; blk < 128; ++blk) {
#pragma unroll 4
    for (int j = 0; j < 16; ++j) {
      int t = blk * 16 + j;
      size_t base = base0 + (size_t)t * 1024;
      float ve = V[base + col];
      const float4* kp = (const float4*)(Kf + base + rp * 16);
      const float4* qp = (const float4*)(Q + base + rp * 16);
      float4 kv[4], qv[4];
#pragma unroll
      for (int g = 0; g < 4; ++g) { kv[g] = kp[g]; qv[g] = qp[g]; }
      int rwi = rwbase0 + t * 32;
      float r = R[rwi];
      float w = Wsm[rwi];
      float mval = mask[b * TSEQ + t];
      float po;
      if (mval > 0.f) {
        float acc = 0.f;
#pragma unroll
        for (int g = 0; g < 4; ++g) {
          s[g*4+0] = s[g*4+0] * r + kv[g].x * ve; acc += qv[g].x * s[g*4+0];
          s[g*4+1] = s[g*4+1] * r + kv[g].y * ve; acc += qv[g].y * s[g*4+1];
          s[g*4+2] = s[g*4+2] * r + kv[g].z * ve; acc += qv[g].z * s[g*4+2];
          s[g*4+3] = s[g*4+3] * r + kv[g].w * ve; acc += qv[g].w * s[g*4+3];
        }
        po = w * acc;
      } else {
        po = 0.f;
      }
      po_lds[e][j][kk * 8 + rp] = po;
    }
    __syncthreads();
    if (tid < 128) {
      int ee = tid & 7, j = tid >> 3;
      const float4* p4 = (const float4*)&po_lds[ee][j][0];
      float4 a0 = p4[0], a1 = p4[1], a2 = p4[2], a3 = p4[3];
      float4 a4 = p4[4], a5 = p4[5], a6 = p4[6], a7 = p4[7];
      float sum = a0.x + a0.y + a0.z + a0.w + a1.x + a1.y + a1.z + a1.w
                + a2.x + a2.y + a2.z + a2.w + a3.x + a3.y + a3.z + a3.w
                + a4.x + a4.y + a4.z + a4.w + a5.x + a5.y + a5.z + a5.w
                + a6.x + a6.y + a6.z + a6.w + a7.x + a7.y + a7.z + a7.w;
      int t = blk * 16 + j;
      O[(size_t)(b * TSEQ + t) * 1024 + h * 128 + cg * 8 + ee] = f2bf(sum);
    }
    __syncthreads();
  }
}

// ------------- LayerNorm (two-pass, per row) -> f32 out -------------
__global__ __launch_bounds__(256) void ln_kernel(const float* __restrict__ Y,
    const float* __restrict__ g, const float* __restrict__ bta,
    float* __restrict__ out) {
  int row = blockIdx.x;
  int tid = threadIdx.x;
  int lane = tid & 63, wave = tid >> 6;
  __shared__ float red[8];
  const float* yr = Y + (size_t)row * 1024;
  float4 v = *(const float4*)(yr + tid * 4);
  float sum = v.x + v.y + v.z + v.w;
#pragma unroll
  for (int off = 32; off > 0; off >>= 1) sum += __shfl_down(sum, off);
  if (lane == 0) red[wave] = sum;
  __syncthreads();
  float mu = (red[0] + red[1] + red[2] + red[3]) * (1.f / 1024.f);
  float4 d;
  d.x = v.x - mu; d.y = v.y - mu; d.z = v.z - mu; d.w = v.w - mu;
  float sq = d.x * d.x + d.y * d.y + d.z * d.z + d.w * d.w;
#pragma unroll
  for (int off = 32; off > 0; off >>= 1) sq += __shfl_down(sq, off);
  __syncthreads();
  if (lane == 0) red[4 + wave] = sq;
  __syncthreads();
  float var = (red[4] + red[5] + red[6] + red[7]) * (1.f / 1024.f);
  float inv = rsqrtf(var + 1e-5f);
  float4 gg = *(const float4*)(g + tid * 4);
  float4 bb4 = *(const float4*)(bta + tid * 4);
  float4 o;
  o.x = d.x * inv * gg.x + bb4.x;
  o.y = d.y * inv * gg.y + bb4.y;
  o.z = d.z * inv * gg.z + bb4.z;
  o.w = d.w * inv * gg.w + bb4.w;
  *(float4*)(out + (size_t)row * 1024 + tid * 4) = o;
}

extern "C" void kernel_launch(void* const* d_in, const int* in_sizes, int n_in,
                              void* d_out, int out_size, void* d_ws, size_t ws_size,
                              hipStream_t stream) {
  const float* x    = (const float*)d_in[0];
  const float* mask = (const float*)d_in[1];
  const float* Wq   = (const float*)d_in[2];
  const float* Wk   = (const float*)d_in[3];
  const float* Wv   = (const float*)d_in[4];
  const float* Wb   = (const float*)d_in[5];
  const float* bb   = (const float*)d_in[6];
  const float* Wm   = (const float*)d_in[7];
  const float* bm   = (const float*)d_in[8];
  const float* Wo   = (const float*)d_in[9];
  const float* bo   = (const float*)d_in[10];
  const float* base_logit = (const float*)d_in[11];
  const float* ln_g = (const float*)d_in[12];
  const float* ln_b = (const float*)d_in[13];

  char* ws = (char*)d_ws;
  const size_t MB = 1024u * 1024u;
  unsigned short* Xb  = (unsigned short*)(ws + 0);          // 8 MiB
  unsigned short* Wtq = (unsigned short*)(ws + 8 * MB);     // 2 MiB
  unsigned short* Wtk = (unsigned short*)(ws + 10 * MB);    // 2 MiB
  unsigned short* Wtv = (unsigned short*)(ws + 12 * MB);    // 2 MiB
  unsigned short* Wto = (unsigned short*)(ws + 14 * MB);    // 2 MiB
  float* Rf  = (float*)(ws + 16 * MB);                      // 0.5 MiB
  float* Wsf = (float*)(ws + 16 * MB + 512 * 1024);         // 0.5 MiB
  float* Qf  = (float*)(ws + 17 * MB);                      // 16 MiB
  float* Kff = (float*)(ws + 33 * MB);                      // 16 MiB
  float* Vf  = (float*)(ws + 49 * MB);                      // 16 MiB
  unsigned short* Ob = (unsigned short*)(ws + 65 * MB);     // 8 MiB
  float* Yf = Qf;  // alias: Q dead after scan, Y written after scan
  if (ws_size < 73 * MB) return;  // fail loudly (validation will catch)

  cast_x_kernel<<<4096, 256, 0, stream>>>(x, Xb);
  dim3 tb(32, 8), tg(32, 32);
  transpose_w_kernel<<<tg, tb, 0, stream>>>(Wq, Wtq);
  transpose_w_kernel<<<tg, tb, 0, stream>>>(Wk, Wtk);
  transpose_w_kernel<<<tg, tb, 0, stream>>>(Wv, Wtv);
  transpose_w_kernel<<<tg, tb, 0, stream>>>(Wo, Wto);

  dim3 gg(8, 32);  // N/128, M/128
  gemm128_kernel<1><<<gg, 256, 0, stream>>>(Xb, Wtq, Qf, nullptr, nullptr);
  gemm128_kernel<1><<<gg, 256, 0, stream>>>(Xb, Wtk, Kff, nullptr, nullptr);
  gemm128_kernel<0><<<gg, 256, 0, stream>>>(Xb, Wtv, Vf, nullptr, nullptr);

  small_rw_kernel<<<4096, 256, 0, stream>>>(x, Wb, bb, Wm, bm, base_logit, Rf, Wsf);

  scan_kernel<<<256, 256, 0, stream>>>(Qf, Kff, Vf, Rf, Wsf, mask, Ob);

  gemm128_kernel<2><<<gg, 256, 0, stream>>>(Ob, Wto, Yf, bo, x);

  ln_kernel<<<4096, 256, 0, stream>>>(Yf, ln_g, ln_b, (unsigned short*)d_out ? (float*)d_out : nullptr);
}

// Round 3
// 668.894 us; speedup vs baseline: 2.2465x; 2.2465x over previous
//
#include <hip/hip_runtime.h>
#include <hip/hip_bf16.h>
#include <math.h>

#define TSEQ 2048
#define NHID 1024

typedef float f32x4 __attribute__((ext_vector_type(4)));
typedef __bf16 bf16x8 __attribute__((ext_vector_type(8)));

static __device__ __forceinline__ unsigned short f2bf(float f) {
  unsigned u = __float_as_uint(f);
  u += 0x7fffu + ((u >> 16) & 1u);
  return (unsigned short)(u >> 16);
}
static __device__ __forceinline__ float bf2f(unsigned short h) {
  return __uint_as_float(((unsigned)h) << 16);
}

// ---------------- cast x (f32) -> bf16 ----------------
__global__ __launch_bounds__(256) void cast_x_kernel(const float* __restrict__ X,
                                                     unsigned short* __restrict__ Xb) {
  int i = (blockIdx.x * 256 + threadIdx.x) * 4;
  float4 v = *(const float4*)(X + i);
  ushort4 o;
  o.x = f2bf(v.x); o.y = f2bf(v.y); o.z = f2bf(v.z); o.w = f2bf(v.w);
  *(ushort4*)(Xb + i) = o;
}

// ------------- transpose 1024x1024 f32 (K,N) -> bf16 (N,K) -------------
__global__ __launch_bounds__(256) void transpose_w_kernel(const float* __restrict__ W,
                                                          unsigned short* __restrict__ Wt) {
  __shared__ float tile[32][33];
  int bx = blockIdx.x * 32;
  int by = blockIdx.y * 32;
  int tx = threadIdx.x, ty = threadIdx.y;
#pragma unroll
  for (int i = 0; i < 32; i += 8)
    tile[ty + i][tx] = W[(size_t)(by + ty + i) * NHID + bx + tx];
  __syncthreads();
#pragma unroll
  for (int i = 0; i < 32; i += 8)
    Wt[(size_t)(bx + ty + i) * NHID + by + tx] = f2bf(tile[tx][ty + i]);
}

// ------------- bf16 MFMA GEMM: C[4096][1024] = epi(A @ Bt^T) -------------
// EPI: 0 = identity->bf16, 1 = elu+1 ->bf16, 2 = +bias[col]+res ->f32
template <int EPI>
__global__ __launch_bounds__(256) void gemm128_kernel(const unsigned short* __restrict__ A,
                                                      const unsigned short* __restrict__ Bt,
                                                      void* __restrict__ Cout,
                                                      const float* __restrict__ bias,
                                                      const float* __restrict__ res) {
  __shared__ __align__(16) unsigned short As[128][32];
  __shared__ __align__(16) unsigned short Bs[128][32];
  const int tid = threadIdx.x;
  const int lane = tid & 63;
  const int wave = tid >> 6;
  const int wr = wave >> 1, wc = wave & 1;
  const int rowBase = blockIdx.y * 128;
  const int colBase = blockIdx.x * 128;

  const int c0 = tid, c1 = tid + 256;
  const int r0 = c0 >> 2, kc0 = c0 & 3, sl0 = kc0 ^ ((r0 >> 1) & 3);
  const int r1 = c1 >> 2, kc1 = c1 & 3, sl1 = kc1 ^ ((r1 >> 1) & 3);

  const int kq = lane >> 4;
  const int r16 = lane & 15;

  f32x4 acc[4][4] = {};

  for (int k0 = 0; k0 < 1024; k0 += 32) {
    bf16x8 a0 = *(const bf16x8*)(A + (size_t)(rowBase + r0) * 1024 + k0 + kc0 * 8);
    bf16x8 a1 = *(const bf16x8*)(A + (size_t)(rowBase + r1) * 1024 + k0 + kc1 * 8);
    bf16x8 b0 = *(const bf16x8*)(Bt + (size_t)(colBase + r0) * 1024 + k0 + kc0 * 8);
    bf16x8 b1 = *(const bf16x8*)(Bt + (size_t)(colBase + r1) * 1024 + k0 + kc1 * 8);
    __syncthreads();
    *(bf16x8*)&As[r0][sl0 * 8] = a0;
    *(bf16x8*)&As[r1][sl1 * 8] = a1;
    *(bf16x8*)&Bs[r0][sl0 * 8] = b0;
    *(bf16x8*)&Bs[r1][sl1 * 8] = b1;
    __syncthreads();
    bf16x8 af[4], bfr[4];
#pragma unroll
    for (int m = 0; m < 4; ++m) {
      int row = wr * 64 + m * 16 + r16;
      af[m] = *(const bf16x8*)&As[row][(kq ^ ((row >> 1) & 3)) * 8];
      int colr = wc * 64 + m * 16 + r16;
      bfr[m] = *(const bf16x8*)&Bs[colr][(kq ^ ((colr >> 1) & 3)) * 8];
    }
#pragma unroll
    for (int m = 0; m < 4; ++m)
#pragma unroll
      for (int n = 0; n < 4; ++n)
        acc[m][n] = __builtin_amdgcn_mfma_f32_16x16x32_bf16(af[m], bfr[n], acc[m][n], 0, 0, 0);
  }

  const int r4 = (lane >> 4) * 4;
#pragma unroll
  for (int m = 0; m < 4; ++m) {
#pragma unroll
    for (int n = 0; n < 4; ++n) {
      int col = colBase + wc * 64 + n * 16 + r16;
#pragma unroll
      for (int j = 0; j < 4; ++j) {
        int row = rowBase + wr * 64 + m * 16 + r4 + j;
        float v = acc[m][n][j];
        if (EPI == 1) v = (v > 0.f) ? (v + 1.f) : expf(v);
        if (EPI == 2) {
          v += bias[col] + res[(size_t)row * 1024 + col];
          ((float*)Cout)[(size_t)row * 1024 + col] = v;
        } else {
          ((unsigned short*)Cout)[(size_t)row * 1024 + col] = f2bf(v);
        }
      }
    }
  }
}

// ------------- per-(b,t): decay r_eff and softmax mix weights -------------
__global__ __launch_bounds__(256) void small_rw_kernel(const float* __restrict__ x,
    const float* __restrict__ Wb, const float* __restrict__ bb,
    const float* __restrict__ Wm, const float* __restrict__ bm,
    const float* __restrict__ base_logit,
    float* __restrict__ R, float* __restrict__ Wsm) {
  int row = blockIdx.x;
  __shared__ float xs[1024];
  __shared__ float outs[40];
  int tid = threadIdx.x;
  const float* xr = x + (size_t)row * 1024;
  for (int i = tid; i < 1024; i += 256) xs[i] = xr[i];
  __syncthreads();
  int wave = tid >> 6, lane = tid & 63;
  for (int o = wave; o < 40; o += 4) {
    float sum = 0.f;
    if (o < 8) {
      for (int i = lane; i < 1024; i += 64) sum += xs[i] * Wb[i * 8 + o];
    } else {
      int c = o - 8;
      for (int i = lane; i < 1024; i += 64) sum += xs[i] * Wm[i * 32 + c];
    }
#pragma unroll
    for (int off = 32; off > 0; off >>= 1) sum += __shfl_down(sum, off);
    if (lane == 0) outs[o] = sum;
  }
  __syncthreads();
  if (tid < 32) {
    int h = tid >> 2;
    float beta = 1.f / (1.f + expf(-(outs[h] + bb[h])));
    float br = 1.f / (1.f + expf(-base_logit[tid]));
    float r = fminf(fmaxf(beta * br, 0.f), 0.999995f);
    float mval = outs[8 + tid] + bm[tid];
    float mx = fmaxf(mval, __shfl_xor(mval, 1));
    mx = fmaxf(mx, __shfl_xor(mx, 2));
    float ex = expf(mval - mx);
    float ssum = ex + __shfl_xor(ex, 1);
    ssum += __shfl_xor(ssum, 2);
    R[(size_t)row * 32 + tid] = r;
    Wsm[(size_t)row * 32 + tid] = ex / ssum;
  }
}

// ------------- decay precompute: WA = w*a, IA = 1/a, DU = aC/a, AC -------------
// chains: (bh, k, chunk) ; a = within-chunk cumprod of r' (r'=1 if masked)
__global__ __launch_bounds__(256) void decay_kernel(const float* __restrict__ R,
    const float* __restrict__ Wsm, const float* __restrict__ mask,
    float* __restrict__ WA, float* __restrict__ IA, float* __restrict__ DU,
    float* __restrict__ AC) {
  int id = blockIdx.x * 256 + threadIdx.x;
  if (id >= 1024) return;
  int c = id & 15, k = (id >> 4) & 3, bh = id >> 6;
  int b = bh >> 3, h = bh & 7;
  int t0 = c * 128;
  float a = 1.f;
  for (int t = 0; t < 128; ++t) {
    int row = b * TSEQ + t0 + t;
    float m = mask[row];
    float rr = (m > 0.f) ? R[(size_t)row * 32 + h * 4 + k] : 1.f;
    a = fmaxf(a * rr, 1e-25f);
  }
  float aC = a;
  AC[(bh * 16 + c) * 4 + k] = aC;
  a = 1.f;
  for (int t = 0; t < 128; ++t) {
    int row = b * TSEQ + t0 + t;
    float m = mask[row];
    float rr = (m > 0.f) ? R[(size_t)row * 32 + h * 4 + k] : 1.f;
    a = fmaxf(a * rr, 1e-25f);
    size_t idx = (size_t)row * 32 + h * 4 + k;
    bool v = (m > 0.f);
    float w = Wsm[idx];
    WA[idx] = v ? w * a : 0.f;
    IA[idx] = v ? 1.f / a : 0.f;
    DU[((bh * 16 + c) * 4 + k) * 128 + t] = v ? aC / a : 0.f;
  }
}

// ------------- kernel A: per (bh,chunk): local attention-form + U^T -------------
// 512 threads (8 waves); wave owns 16 t-rows (QK/PV) and 16 dv-rows (U^T).
__global__ __launch_bounds__(512) void chunkA_kernel(
    const unsigned short* __restrict__ Qb, const unsigned short* __restrict__ Kb,
    const unsigned short* __restrict__ Vb,
    const float* __restrict__ WA, const float* __restrict__ IA,
    const float* __restrict__ DU,
    float* __restrict__ Olocal, unsigned short* __restrict__ UT) {
  __shared__ __align__(16) char KTl[32768];  // K^T [dk][t] swizzled
  __shared__ __align__(16) char VTl[32768];  // V^T [dv][t] swizzled
  __shared__ __align__(16) char Pl[32768];   // P [t][j] swizzled
  __shared__ __align__(16) float WAl[128][4];
  __shared__ __align__(16) float IAl[128][4];
  __shared__ float DUl[4][128];

  int wg = blockIdx.x;
  int bh = wg >> 4, c = wg & 15;
  int b = bh >> 3, h = bh & 7;
  int t0 = c * 128;
  int tid = threadIdx.x;
  int lane = tid & 63, wave = tid >> 6;
  int wbase = wave * 16;
  int l15 = lane & 15, lq = lane >> 4;

  const size_t qkvbase = ((size_t)b * TSEQ + t0) * 1024 + h * 128;

  // ---- staging: K^T and V^T (scatter, swizzled) ----
  for (int it = 0; it < 4; ++it) {
    int ci = tid + it * 512;           // 0..2047 : 16B chunk id
    int t = ci >> 4, s = ci & 15;
    bf16x8 kv = *(const bf16x8*)(Kb + qkvbase + (size_t)t * 1024 + s * 8);
    bf16x8 vv = *(const bf16x8*)(Vb + qkvbase + (size_t)t * 1024 + s * 8);
#pragma unroll
    for (int e = 0; e < 8; ++e) {
      int d = s * 8 + e;
      int off = d * 256 + (((t >> 3) ^ (d & 7)) << 4) + (t & 7) * 2;
      *(unsigned short*)(KTl + off) = f2bf((float)kv[e]);
      *(unsigned short*)(VTl + off) = f2bf((float)vv[e]);
    }
  }
  {
    int t = tid >> 2, k = tid & 3;
    size_t idx = ((size_t)b * TSEQ + t0 + t) * 32 + h * 4 + k;
    WAl[t][k] = WA[idx];
    IAl[t][k] = IA[idx];
    int k2 = tid >> 7, j = tid & 127;
    DUl[k2][j] = DU[((bh * 16 + c) * 4 + k2) * 128 + j];
  }
  __syncthreads();

  // ---- QK^T (Q,K frags direct from global, L1-resident) ----
  bf16x8 qf[4];
#pragma unroll
  for (int ds = 0; ds < 4; ++ds)
    qf[ds] = *(const bf16x8*)(Qb + qkvbase + (size_t)(wbase + l15) * 1024 + ds * 32 + lq * 8);
  f32x4 accP[8];
#pragma unroll
  for (int jf = 0; jf < 8; ++jf) {
    f32x4 a = {};
#pragma unroll
    for (int ds = 0; ds < 4; ++ds) {
      bf16x8 kfrag = *(const bf16x8*)(Kb + qkvbase + (size_t)(jf * 16 + l15) * 1024 + ds * 32 + lq * 8);
      a = __builtin_amdgcn_mfma_f32_16x16x32_bf16(qf[ds], kfrag, a, 0, 0, 0);
    }
    accP[jf] = a;
  }

  // ---- mask/decay -> P (bf16, swizzled LDS) ----
  float4 wa4[4];
#pragma unroll
  for (int jj = 0; jj < 4; ++jj)
    wa4[jj] = *(const float4*)&WAl[wbase + lq * 4 + jj][0];
#pragma unroll
  for (int jf = 0; jf < 8; ++jf) {
    float4 ia4 = *(const float4*)&IAl[jf * 16 + l15][0];
#pragma unroll
    for (int jj = 0; jj < 4; ++jj) {
      int tl = wbase + lq * 4 + jj;
      int jl = jf * 16 + l15;
      float m = 0.f;
      if (jl <= tl)
        m = wa4[jj].x * ia4.x + wa4[jj].y * ia4.y + wa4[jj].z * ia4.z + wa4[jj].w * ia4.w;
      float pv = accP[jf][jj] * m;
      int off = tl * 256 + (((jl >> 3) ^ (tl & 7)) << 4) + (jl & 7) * 2;
      *(unsigned short*)(Pl + off) = f2bf(pv);
    }
  }
  // same-wave LDS RAW: in-order, no barrier needed

  // ---- PV -> Olocal ----
  bf16x8 pf[4];
#pragma unroll
  for (int js = 0; js < 4; ++js) {
    int tl = wbase + l15;
    int slot = js * 4 + lq;
    pf[js] = *(const bf16x8*)(Pl + tl * 256 + ((slot ^ (tl & 7)) << 4));
  }
#pragma unroll
  for (int dvf = 0; dvf < 8; ++dvf) {
    f32x4 a = {};
    int dv = dvf * 16 + l15;
#pragma unroll
    for (int js = 0; js < 4; ++js) {
      int slot = js * 4 + lq;
      bf16x8 vfrag = *(const bf16x8*)(VTl + dv * 256 + ((slot ^ (dv & 7)) << 4));
      a = __builtin_amdgcn_mfma_f32_16x16x32_bf16(pf[js], vfrag, a, 0, 0, 0);
    }
#pragma unroll
    for (int jj = 0; jj < 4; ++jj) {
      int tl = wbase + lq * 4 + jj;
      Olocal[((size_t)b * TSEQ + t0 + tl) * 1024 + h * 128 + dv] = a[jj];
    }
  }

  // ---- U^T = (DU*V)^T K : per k, acc (dv x dk) ----
  if (c < 15) {
#pragma unroll 1
    for (int k = 0; k < 4; ++k) {
      f32x4 accU[8] = {};
#pragma unroll 1
      for (int js = 0; js < 4; ++js) {
        int dvr = wbase + l15;
        int slot = js * 4 + lq;
        bf16x8 af = *(const bf16x8*)(VTl + dvr * 256 + ((slot ^ (dvr & 7)) << 4));
        int j0 = js * 32 + lq * 8;
        bf16x8 afs;
#pragma unroll
        for (int e = 0; e < 8; ++e)
          afs[e] = (__bf16)((float)af[e] * DUl[k][j0 + e]);
#pragma unroll
        for (int dkf = 0; dkf < 8; ++dkf) {
          int dk = dkf * 16 + l15;
          bf16x8 kf = *(const bf16x8*)(KTl + dk * 256 + ((slot ^ (dk & 7)) << 4));
          accU[dkf] = __builtin_amdgcn_mfma_f32_16x16x32_bf16(afs, kf, accU[dkf], 0, 0, 0);
        }
      }
      size_t ub = (((size_t)bh * 16 + c) * 4 + k) * 16384;
#pragma unroll
      for (int dkf = 0; dkf < 8; ++dkf) {
        int dk = dkf * 16 + l15;
#pragma unroll
        for (int jj = 0; jj < 4; ++jj) {
          int dvr = wbase + lq * 4 + jj;
          UT[ub + (size_t)dvr * 128 + dk] = f2bf(accU[dkf][jj]);
        }
      }
    }
  }
}

// ------------- kernel B: chain states S <- aC*S + U (elementwise over chunks) -------------
__global__ __launch_bounds__(256) void chainB_kernel(const unsigned short* __restrict__ UT,
    const float* __restrict__ AC, unsigned short* __restrict__ S0T) {
  int id = blockIdx.x * 256 + threadIdx.x;   // 1,048,576 = 16*4*128*128
  int dk = id & 127;
  int dv = (id >> 7) & 127;
  int k = (id >> 14) & 3;
  int bh = id >> 16;
  size_t elem = (size_t)dv * 128 + dk;
  float S = 0.f;
#pragma unroll 1
  for (int c = 0; c < 15; ++c) {
    size_t ub = (((size_t)bh * 16 + c) * 4 + k) * 16384;
    float u = bf2f(UT[ub + elem]);
    float aC = AC[(bh * 16 + c) * 4 + k];
    S = aC * S + u;
    size_t sb = (((size_t)bh * 16 + (c + 1)) * 4 + k) * 16384;
    S0T[sb + elem] = f2bf(S);
  }
}

// ------------- kernel C: cross-chunk O += sum_k diag(w*a) Q @ S0^k ; emit Ob bf16 -------------
__global__ __launch_bounds__(512) void chunkC_kernel(const unsigned short* __restrict__ Qb,
    const unsigned short* __restrict__ S0T, const float* __restrict__ WA,
    const float* __restrict__ Olocal, unsigned short* __restrict__ Ob) {
  __shared__ __align__(16) char Sl[32768];
  int wg = blockIdx.x;
  int bh = wg >> 4, c = wg & 15;
  int b = bh >> 3, h = bh & 7;
  int t0 = c * 128;
  int tid = threadIdx.x, lane = tid & 63, wave = tid >> 6;
  int l15 = lane & 15, lq = lane >> 4, wbase = wave * 16;
  size_t qbase = ((size_t)b * TSEQ + t0) * 1024 + h * 128;

  f32x4 accO[8] = {};
  if (c > 0) {
    int tl = wbase + l15;
#pragma unroll 1
    for (int k = 0; k < 4; ++k) {
      __syncthreads();
      size_t sb = (((size_t)bh * 16 + c) * 4 + k) * 16384;
      for (int it = 0; it < 4; ++it) {
        int ci = tid + it * 512;
        int dv = ci >> 4, s = ci & 15;
        bf16x8 vv = *(const bf16x8*)(S0T + sb + (size_t)dv * 128 + s * 8);
        *(bf16x8*)(Sl + dv * 256 + ((s ^ (dv & 7)) << 4)) = vv;
      }
      __syncthreads();
      float sc = WA[((size_t)b * TSEQ + t0 + tl) * 32 + h * 4 + k];
#pragma unroll 1
      for (int ds = 0; ds < 4; ++ds) {
        bf16x8 qf = *(const bf16x8*)(Qb + qbase + (size_t)tl * 1024 + ds * 32 + lq * 8);
        bf16x8 qs;
#pragma unroll
        for (int e = 0; e < 8; ++e) qs[e] = (__bf16)((float)qf[e] * sc);
#pragma unroll
        for (int dvf = 0; dvf < 8; ++dvf) {
          int dv = dvf * 16 + l15;
          int slot = ds * 4 + lq;
          bf16x8 sf = *(const bf16x8*)(Sl + dv * 256 + ((slot ^ (dv & 7)) << 4));
          accO[dvf] = __builtin_amdgcn_mfma_f32_16x16x32_bf16(qs, sf, accO[dvf], 0, 0, 0);
        }
      }
    }
  }
#pragma unroll
  for (int dvf = 0; dvf < 8; ++dvf) {
    int dv = dvf * 16 + l15;
#pragma unroll
    for (int jj = 0; jj < 4; ++jj) {
      int tl = wbase + lq * 4 + jj;
      size_t off = ((size_t)b * TSEQ + t0 + tl) * 1024 + h * 128 + dv;
      Ob[off] = f2bf(accO[dvf][jj] + Olocal[off]);
    }
  }
}

// ------------- LayerNorm (two-pass, per row) -> f32 out -------------
__global__ __launch_bounds__(256) void ln_kernel(const float* __restrict__ Y,
    const float* __restrict__ g, const float* __restrict__ bta,
    float* __restrict__ out) {
  int row = blockIdx.x;
  int tid = threadIdx.x;
  int lane = tid & 63, wave = tid >> 6;
  __shared__ float red[8];
  const float* yr = Y + (size_t)row * 1024;
  float4 v = *(const float4*)(yr + tid * 4);
  float sum = v.x + v.y + v.z + v.w;
#pragma unroll
  for (int off = 32; off > 0; off >>= 1) sum += __shfl_down(sum, off);
  if (lane == 0) red[wave] = sum;
  __syncthreads();
  float mu = (red[0] + red[1] + red[2] + red[3]) * (1.f / 1024.f);
  float4 d;
  d.x = v.x - mu; d.y = v.y - mu; d.z = v.z - mu; d.w = v.w - mu;
  float sq = d.x * d.x + d.y * d.y + d.z * d.z + d.w * d.w;
#pragma unroll
  for (int off = 32; off > 0; off >>= 1) sq += __shfl_down(sq, off);
  __syncthreads();
  if (lane == 0) red[4 + wave] = sq;
  __syncthreads();
  float var = (red[4] + red[5] + red[6] + red[7]) * (1.f / 1024.f);
  float inv = rsqrtf(var + 1e-5f);
  float4 gg = *(const float4*)(g + tid * 4);
  float4 bb4 = *(const float4*)(bta + tid * 4);
  float4 o;
  o.x = d.x * inv * gg.x + bb4.x;
  o.y = d.y * inv * gg.y + bb4.y;
  o.z = d.z * inv * gg.z + bb4.z;
  o.w = d.w * inv * gg.w + bb4.w;
  *(float4*)(out + (size_t)row * 1024 + tid * 4) = o;
}

extern "C" void kernel_launch(void* const* d_in, const int* in_sizes, int n_in,
                              void* d_out, int out_size, void* d_ws, size_t ws_size,
                              hipStream_t stream) {
  const float* x    = (const float*)d_in[0];
  const float* mask = (const float*)d_in[1];
  const float* Wq   = (const float*)d_in[2];
  const float* Wk   = (const float*)d_in[3];
  const float* Wv   = (const float*)d_in[4];
  const float* Wb   = (const float*)d_in[5];
  const float* bb   = (const float*)d_in[6];
  const float* Wm   = (const float*)d_in[7];
  const float* bm   = (const float*)d_in[8];
  const float* Wo   = (const float*)d_in[9];
  const float* bo   = (const float*)d_in[10];
  const float* base_logit = (const float*)d_in[11];
  const float* ln_g = (const float*)d_in[12];
  const float* ln_b = (const float*)d_in[13];

  char* ws = (char*)d_ws;
  const size_t MB = 1024u * 1024u;
  unsigned short* Xb  = (unsigned short*)(ws + 0);
  unsigned short* Wtq = (unsigned short*)(ws + 8 * MB);
  unsigned short* Wtk = (unsigned short*)(ws + 10 * MB);
  unsigned short* Wtv = (unsigned short*)(ws + 12 * MB);
  unsigned short* Wto = (unsigned short*)(ws + 14 * MB);
  float* Rf  = (float*)(ws + 16 * MB);
  float* Wsf = (float*)(ws + 16 * MB + 512 * 1024);
  float* WAf = (float*)(ws + 17 * MB);
  float* IAf = (float*)(ws + 17 * MB + 512 * 1024);
  float* DUf = (float*)(ws + 18 * MB);
  float* ACf = (float*)(ws + 18 * MB + 512 * 1024);
  unsigned short* Qb = (unsigned short*)(ws + 19 * MB);
  unsigned short* Kb = (unsigned short*)(ws + 27 * MB);
  unsigned short* Vb = (unsigned short*)(ws + 35 * MB);
  float* Olocal = (float*)(ws + 43 * MB);            // 16 MB
  unsigned short* Ob = (unsigned short*)(ws + 59 * MB);  // 8 MB
  unsigned short* UTb = (unsigned short*)(ws + 67 * MB); // 32 MB
  unsigned short* S0T = (unsigned short*)(ws + 99 * MB); // 32 MB
  float* Yf = Olocal;  // alias: Olocal dead after chunkC
  if (ws_size < 131 * MB) return;

  cast_x_kernel<<<4096, 256, 0, stream>>>(x, Xb);
  dim3 tb(32, 8), tg(32, 32);
  transpose_w_kernel<<<tg, tb, 0, stream>>>(Wq, Wtq);
  transpose_w_kernel<<<tg, tb, 0, stream>>>(Wk, Wtk);
  transpose_w_kernel<<<tg, tb, 0, stream>>>(Wv, Wtv);
  transpose_w_kernel<<<tg, tb, 0, stream>>>(Wo, Wto);

  dim3 gg(8, 32);
  gemm128_kernel<1><<<gg, 256, 0, stream>>>(Xb, Wtq, Qb, nullptr, nullptr);
  gemm128_kernel<1><<<gg, 256, 0, stream>>>(Xb, Wtk, Kb, nullptr, nullptr);
  gemm128_kernel<0><<<gg, 256, 0, stream>>>(Xb, Wtv, Vb, nullptr, nullptr);

  small_rw_kernel<<<4096, 256, 0, stream>>>(x, Wb, bb, Wm, bm, base_logit, Rf, Wsf);
  decay_kernel<<<4, 256, 0, stream>>>(Rf, Wsf, mask, WAf, IAf, DUf, ACf);

  chunkA_kernel<<<256, 512, 0, stream>>>(Qb, Kb, Vb, WAf, IAf, DUf, Olocal, UTb);
  chainB_kernel<<<4096, 256, 0, stream>>>(UTb, ACf, S0T);
  chunkC_kernel<<<256, 512, 0, stream>>>(Qb, S0T, WAf, Olocal, Ob);

  gemm128_kernel<2><<<gg, 256, 0, stream>>>(Ob, Wto, Yf, bo, x);

  ln_kernel<<<4096, 256, 0, stream>>>(Yf, ln_g, ln_b, (float*)d_out);
}

// Round 4
// 220.349 us; speedup vs baseline: 6.8194x; 3.0356x over previous
//
#include <hip/hip_runtime.h>
#include <hip/hip_bf16.h>
#include <math.h>

#define TSEQ 2048
#define NHID 1024

typedef float f32x4 __attribute__((ext_vector_type(4)));
typedef __bf16 bf16x8 __attribute__((ext_vector_type(8)));

static __device__ __forceinline__ unsigned short f2bf(float f) {
  unsigned u = __float_as_uint(f);
  u += 0x7fffu + ((u >> 16) & 1u);
  return (unsigned short)(u >> 16);
}
static __device__ __forceinline__ float bf2f(unsigned short h) {
  return __uint_as_float(((unsigned)h) << 16);
}

// ---------------- cast x (f32) -> bf16 ----------------
__global__ __launch_bounds__(256) void cast_x_kernel(const float* __restrict__ X,
                                                     unsigned short* __restrict__ Xb) {
  int i = (blockIdx.x * 256 + threadIdx.x) * 4;
  float4 v = *(const float4*)(X + i);
  ushort4 o;
  o.x = f2bf(v.x); o.y = f2bf(v.y); o.z = f2bf(v.z); o.w = f2bf(v.w);
  *(ushort4*)(Xb + i) = o;
}

// ------------- transpose 1024x1024 f32 (K,N) -> bf16 (N,K) -------------
__global__ __launch_bounds__(256) void transpose_w_kernel(const float* __restrict__ W,
                                                          unsigned short* __restrict__ Wt) {
  __shared__ float tile[32][33];
  int bx = blockIdx.x * 32;
  int by = blockIdx.y * 32;
  int tx = threadIdx.x, ty = threadIdx.y;
#pragma unroll
  for (int i = 0; i < 32; i += 8)
    tile[ty + i][tx] = W[(size_t)(by + ty + i) * NHID + bx + tx];
  __syncthreads();
#pragma unroll
  for (int i = 0; i < 32; i += 8)
    Wt[(size_t)(bx + ty + i) * NHID + by + tx] = f2bf(tile[tx][ty + i]);
}

// ------------- bf16 MFMA GEMM: C[4096][1024] = epi(A @ Bt^T) -------------
// EPI: 0 = identity->bf16, 1 = elu+1 ->bf16, 2 = +bias[col]+res ->f32
template <int EPI>
__global__ __launch_bounds__(256) void gemm128_kernel(const unsigned short* __restrict__ A,
                                                      const unsigned short* __restrict__ Bt,
                                                      void* __restrict__ Cout,
                                                      const float* __restrict__ bias,
                                                      const float* __restrict__ res) {
  __shared__ __align__(16) unsigned short As[128][32];
  __shared__ __align__(16) unsigned short Bs[128][32];
  const int tid = threadIdx.x;
  const int lane = tid & 63;
  const int wave = tid >> 6;
  const int wr = wave >> 1, wc = wave & 1;
  const int rowBase = blockIdx.y * 128;
  const int colBase = blockIdx.x * 128;

  const int c0 = tid, c1 = tid + 256;
  const int r0 = c0 >> 2, kc0 = c0 & 3, sl0 = kc0 ^ ((r0 >> 1) & 3);
  const int r1 = c1 >> 2, kc1 = c1 & 3, sl1 = kc1 ^ ((r1 >> 1) & 3);

  const int kq = lane >> 4;
  const int r16 = lane & 15;

  f32x4 acc[4][4] = {};

  for (int k0 = 0; k0 < 1024; k0 += 32) {
    bf16x8 a0 = *(const bf16x8*)(A + (size_t)(rowBase + r0) * 1024 + k0 + kc0 * 8);
    bf16x8 a1 = *(const bf16x8*)(A + (size_t)(rowBase + r1) * 1024 + k0 + kc1 * 8);
    bf16x8 b0 = *(const bf16x8*)(Bt + (size_t)(colBase + r0) * 1024 + k0 + kc0 * 8);
    bf16x8 b1 = *(const bf16x8*)(Bt + (size_t)(colBase + r1) * 1024 + k0 + kc1 * 8);
    __syncthreads();
    *(bf16x8*)&As[r0][sl0 * 8] = a0;
    *(bf16x8*)&As[r1][sl1 * 8] = a1;
    *(bf16x8*)&Bs[r0][sl0 * 8] = b0;
    *(bf16x8*)&Bs[r1][sl1 * 8] = b1;
    __syncthreads();
    bf16x8 af[4], bfr[4];
#pragma unroll
    for (int m = 0; m < 4; ++m) {
      int row = wr * 64 + m * 16 + r16;
      af[m] = *(const bf16x8*)&As[row][(kq ^ ((row >> 1) & 3)) * 8];
      int colr = wc * 64 + m * 16 + r16;
      bfr[m] = *(const bf16x8*)&Bs[colr][(kq ^ ((colr >> 1) & 3)) * 8];
    }
#pragma unroll
    for (int m = 0; m < 4; ++m)
#pragma unroll
      for (int n = 0; n < 4; ++n)
        acc[m][n] = __builtin_amdgcn_mfma_f32_16x16x32_bf16(af[m], bfr[n], acc[m][n], 0, 0, 0);
  }

  const int r4 = (lane >> 4) * 4;
#pragma unroll
  for (int m = 0; m < 4; ++m) {
#pragma unroll
    for (int n = 0; n < 4; ++n) {
      int col = colBase + wc * 64 + n * 16 + r16;
#pragma unroll
      for (int j = 0; j < 4; ++j) {
        int row = rowBase + wr * 64 + m * 16 + r4 + j;
        float v = acc[m][n][j];
        if (EPI == 1) v = (v > 0.f) ? (v + 1.f) : expf(v);
        if (EPI == 2) {
          v += bias[col] + res[(size_t)row * 1024 + col];
          ((float*)Cout)[(size_t)row * 1024 + col] = v;
        } else {
          ((unsigned short*)Cout)[(size_t)row * 1024 + col] = f2bf(v);
        }
      }
    }
  }
}

// ------------- pack Wb (1024x8) | Wm (1024x32) -> Wt f32 [40][1024] -------------
__global__ __launch_bounds__(256) void pack_wbm_kernel(const float* __restrict__ Wb,
    const float* __restrict__ Wm, float* __restrict__ Wt) {
  int id = blockIdx.x * 256 + threadIdx.x;
  if (id >= 40960) return;
  int o = id >> 10, i = id & 1023;
  Wt[id] = (o < 8) ? Wb[i * 8 + o] : Wm[i * 32 + (o - 8)];
}

// ------------- per-(b,t): decay r_eff and softmax mix weights (coalesced W) -------------
__global__ __launch_bounds__(256) void rw2_kernel(const float* __restrict__ x,
    const float* __restrict__ Wt, const float* __restrict__ bb,
    const float* __restrict__ bm, const float* __restrict__ base_logit,
    float* __restrict__ R, float* __restrict__ Wsm) {
  int row = blockIdx.x;
  __shared__ float xs[1024];
  __shared__ float outs[40];
  int tid = threadIdx.x;
  *(float4*)(xs + tid * 4) = *(const float4*)(x + (size_t)row * 1024 + tid * 4);
  __syncthreads();
  int wave = tid >> 6, lane = tid & 63;
  for (int o = wave; o < 40; o += 4) {
    const float* wr = Wt + o * 1024;
    float sum = 0.f;
#pragma unroll
    for (int it = 0; it < 16; ++it) {
      int i = it * 64 + lane;
      sum += xs[i] * wr[i];
    }
#pragma unroll
    for (int off = 32; off > 0; off >>= 1) sum += __shfl_down(sum, off);
    if (lane == 0) outs[o] = sum;
  }
  __syncthreads();
  if (tid < 32) {
    int h = tid >> 2;
    float beta = 1.f / (1.f + expf(-(outs[h] + bb[h])));
    float br = 1.f / (1.f + expf(-base_logit[tid]));
    float r = fminf(fmaxf(beta * br, 0.f), 0.999995f);
    float mval = outs[8 + tid] + bm[tid];
    float mx = fmaxf(mval, __shfl_xor(mval, 1));
    mx = fmaxf(mx, __shfl_xor(mx, 2));
    float ex = expf(mval - mx);
    float ssum = ex + __shfl_xor(ex, 1);
    ssum += __shfl_xor(ssum, 2);
    R[(size_t)row * 32 + tid] = r;
    Wsm[(size_t)row * 32 + tid] = ex / ssum;
  }
}

// ------------- decay precompute via wave product-scan -------------
// one wave per chain (bh,k,chunk); lane handles t=2l,2l+1
__global__ __launch_bounds__(256) void decay2_kernel(const float* __restrict__ R,
    const float* __restrict__ Wsm, const float* __restrict__ mask,
    float* __restrict__ WA, float* __restrict__ IA, float* __restrict__ DU,
    float* __restrict__ AC) {
  int wave = threadIdx.x >> 6, lane = threadIdx.x & 63;
  int id = blockIdx.x * 4 + wave;    // 1024 chains
  int c = id & 15, k = (id >> 4) & 3, bh = id >> 6;
  int b = bh >> 3, h = bh & 7;
  int row0 = b * TSEQ + c * 128 + 2 * lane;
  float m0 = mask[row0], m1 = mask[row0 + 1];
  size_t i0 = (size_t)row0 * 32 + h * 4 + k;
  float rr0 = (m0 > 0.f) ? R[i0] : 1.f;
  float rr1 = (m1 > 0.f) ? R[i0 + 32] : 1.f;
  float incl = rr0 * rr1;
#pragma unroll
  for (int off = 1; off < 64; off <<= 1) {
    float o = __shfl_up(incl, off);
    if (lane >= off) incl *= o;
  }
  float excl = __shfl_up(incl, 1);
  if (lane == 0) excl = 1.f;
  float a0 = fmaxf(excl * rr0, 1e-25f);
  float a1 = fmaxf(a0 * rr1, 1e-25f);
  float aC = __shfl(a1, 63);
  if (lane == 63) AC[(bh * 16 + c) * 4 + k] = a1;
  bool v0 = m0 > 0.f, v1 = m1 > 0.f;
  float w0 = Wsm[i0], w1 = Wsm[i0 + 32];
  int dub = ((bh * 16 + c) * 4 + k) * 128 + 2 * lane;
  WA[i0] = v0 ? w0 * a0 : 0.f;
  WA[i0 + 32] = v1 ? w1 * a1 : 0.f;
  IA[i0] = v0 ? 1.f / a0 : 0.f;
  IA[i0 + 32] = v1 ? 1.f / a1 : 0.f;
  DU[dub] = v0 ? aC / a0 : 0.f;
  DU[dub + 1] = v1 ? aC / a1 : 0.f;
}

// ------------- kernel A: per (bh,chunk): local attention-form + U^T -------------
__global__ __launch_bounds__(512) void chunkA_kernel(
    const unsigned short* __restrict__ Qb, const unsigned short* __restrict__ Kb,
    const unsigned short* __restrict__ Vb,
    const float* __restrict__ WA, const float* __restrict__ IA,
    const float* __restrict__ DU,
    float* __restrict__ Olocal, unsigned short* __restrict__ UT) {
  __shared__ __align__(16) char KTl[32768];  // K^T [dk][t] swizzled
  __shared__ __align__(16) char VTl[32768];  // V^T [dv][t] swizzled
  __shared__ __align__(16) char Pl[32768];   // P [t][j] swizzled
  __shared__ __align__(16) float WAl[128][4];
  __shared__ __align__(16) float IAl[128][4];
  __shared__ float DUl[4][128];

  int wg = blockIdx.x;
  int bh = wg >> 4, c = wg & 15;
  int b = bh >> 3, h = bh & 7;
  int t0 = c * 128;
  int tid = threadIdx.x;
  int lane = tid & 63, wave = tid >> 6;
  int wbase = wave * 16;
  int l15 = lane & 15, lq = lane >> 4;

  const size_t qkvbase = ((size_t)b * TSEQ + t0) * 1024 + h * 128;

  for (int it = 0; it < 4; ++it) {
    int ci = tid + it * 512;
    int t = ci >> 4, s = ci & 15;
    bf16x8 kv = *(const bf16x8*)(Kb + qkvbase + (size_t)t * 1024 + s * 8);
    bf16x8 vv = *(const bf16x8*)(Vb + qkvbase + (size_t)t * 1024 + s * 8);
#pragma unroll
    for (int e = 0; e < 8; ++e) {
      int d = s * 8 + e;
      int off = d * 256 + (((t >> 3) ^ (d & 7)) << 4) + (t & 7) * 2;
      *(unsigned short*)(KTl + off) = f2bf((float)kv[e]);
      *(unsigned short*)(VTl + off) = f2bf((float)vv[e]);
    }
  }
  {
    int t = tid >> 2, k = tid & 3;
    size_t idx = ((size_t)b * TSEQ + t0 + t) * 32 + h * 4 + k;
    WAl[t][k] = WA[idx];
    IAl[t][k] = IA[idx];
    int k2 = tid >> 7, j = tid & 127;
    DUl[k2][j] = DU[((bh * 16 + c) * 4 + k2) * 128 + j];
  }
  __syncthreads();

  bf16x8 qf[4];
#pragma unroll
  for (int ds = 0; ds < 4; ++ds)
    qf[ds] = *(const bf16x8*)(Qb + qkvbase + (size_t)(wbase + l15) * 1024 + ds * 32 + lq * 8);
  f32x4 accP[8];
#pragma unroll
  for (int jf = 0; jf < 8; ++jf) {
    f32x4 a = {};
#pragma unroll
    for (int ds = 0; ds < 4; ++ds) {
      bf16x8 kfrag = *(const bf16x8*)(Kb + qkvbase + (size_t)(jf * 16 + l15) * 1024 + ds * 32 + lq * 8);
      a = __builtin_amdgcn_mfma_f32_16x16x32_bf16(qf[ds], kfrag, a, 0, 0, 0);
    }
    accP[jf] = a;
  }

  float4 wa4[4];
#pragma unroll
  for (int jj = 0; jj < 4; ++jj)
    wa4[jj] = *(const float4*)&WAl[wbase + lq * 4 + jj][0];
#pragma unroll
  for (int jf = 0; jf < 8; ++jf) {
    float4 ia4 = *(const float4*)&IAl[jf * 16 + l15][0];
#pragma unroll
    for (int jj = 0; jj < 4; ++jj) {
      int tl = wbase + lq * 4 + jj;
      int jl = jf * 16 + l15;
      float m = 0.f;
      if (jl <= tl)
        m = wa4[jj].x * ia4.x + wa4[jj].y * ia4.y + wa4[jj].z * ia4.z + wa4[jj].w * ia4.w;
      float pv = accP[jf][jj] * m;
      int off = tl * 256 + (((jl >> 3) ^ (tl & 7)) << 4) + (jl & 7) * 2;
      *(unsigned short*)(Pl + off) = f2bf(pv);
    }
  }

  bf16x8 pf[4];
#pragma unroll
  for (int js = 0; js < 4; ++js) {
    int tl = wbase + l15;
    int slot = js * 4 + lq;
    pf[js] = *(const bf16x8*)(Pl + tl * 256 + ((slot ^ (tl & 7)) << 4));
  }
#pragma unroll
  for (int dvf = 0; dvf < 8; ++dvf) {
    f32x4 a = {};
    int dv = dvf * 16 + l15;
#pragma unroll
    for (int js = 0; js < 4; ++js) {
      int slot = js * 4 + lq;
      bf16x8 vfrag = *(const bf16x8*)(VTl + dv * 256 + ((slot ^ (dv & 7)) << 4));
      a = __builtin_amdgcn_mfma_f32_16x16x32_bf16(pf[js], vfrag, a, 0, 0, 0);
    }
#pragma unroll
    for (int jj = 0; jj < 4; ++jj) {
      int tl = wbase + lq * 4 + jj;
      Olocal[((size_t)b * TSEQ + t0 + tl) * 1024 + h * 128 + dv] = a[jj];
    }
  }

  if (c < 15) {
#pragma unroll 1
    for (int k = 0; k < 4; ++k) {
      f32x4 accU[8] = {};
#pragma unroll 1
      for (int js = 0; js < 4; ++js) {
        int dvr = wbase + l15;
        int slot = js * 4 + lq;
        bf16x8 af = *(const bf16x8*)(VTl + dvr * 256 + ((slot ^ (dvr & 7)) << 4));
        int j0 = js * 32 + lq * 8;
        bf16x8 afs;
#pragma unroll
        for (int e = 0; e < 8; ++e)
          afs[e] = (__bf16)((float)af[e] * DUl[k][j0 + e]);
#pragma unroll
        for (int dkf = 0; dkf < 8; ++dkf) {
          int dk = dkf * 16 + l15;
          bf16x8 kf = *(const bf16x8*)(KTl + dk * 256 + ((slot ^ (dk & 7)) << 4));
          accU[dkf] = __builtin_amdgcn_mfma_f32_16x16x32_bf16(afs, kf, accU[dkf], 0, 0, 0);
        }
      }
      size_t ub = (((size_t)bh * 16 + c) * 4 + k) * 16384;
#pragma unroll
      for (int dkf = 0; dkf < 8; ++dkf) {
        int dk = dkf * 16 + l15;
#pragma unroll
        for (int jj = 0; jj < 4; ++jj) {
          int dvr = wbase + lq * 4 + jj;
          UT[ub + (size_t)dvr * 128 + dk] = f2bf(accU[dkf][jj]);
        }
      }
    }
  }
}

// ------------- kernel B: chain states S <- aC*S + U -------------
__global__ __launch_bounds__(256) void chainB_kernel(const unsigned short* __restrict__ UT,
    const float* __restrict__ AC, unsigned short* __restrict__ S0T) {
  int id = blockIdx.x * 256 + threadIdx.x;
  int dk = id & 127;
  int dv = (id >> 7) & 127;
  int k = (id >> 14) & 3;
  int bh = id >> 16;
  size_t elem = (size_t)dv * 128 + dk;
  float S = 0.f;
#pragma unroll 1
  for (int c = 0; c < 15; ++c) {
    size_t ub = (((size_t)bh * 16 + c) * 4 + k) * 16384;
    float u = bf2f(UT[ub + elem]);
    float aC = AC[(bh * 16 + c) * 4 + k];
    S = aC * S + u;
    size_t sb = (((size_t)bh * 16 + (c + 1)) * 4 + k) * 16384;
    S0T[sb + elem] = f2bf(S);
  }
}

// ------------- kernel C: cross-chunk O += sum_k diag(w*a) Q @ S0^k -------------
__global__ __launch_bounds__(512) void chunkC_kernel(const unsigned short* __restrict__ Qb,
    const unsigned short* __restrict__ S0T, const float* __restrict__ WA,
    const float* __restrict__ Olocal, unsigned short* __restrict__ Ob) {
  __shared__ __align__(16) char Sl[32768];
  int wg = blockIdx.x;
  int bh = wg >> 4, c = wg & 15;
  int b = bh >> 3, h = bh & 7;
  int t0 = c * 128;
  int tid = threadIdx.x, lane = tid & 63, wave = tid >> 6;
  int l15 = lane & 15, lq = lane >> 4, wbase = wave * 16;
  size_t qbase = ((size_t)b * TSEQ + t0) * 1024 + h * 128;

  f32x4 accO[8] = {};
  if (c > 0) {
    int tl = wbase + l15;
#pragma unroll 1
    for (int k = 0; k < 4; ++k) {
      __syncthreads();
      size_t sb = (((size_t)bh * 16 + c) * 4 + k) * 16384;
      for (int it = 0; it < 4; ++it) {
        int ci = tid + it * 512;
        int dv = ci >> 4, s = ci & 15;
        bf16x8 vv = *(const bf16x8*)(S0T + sb + (size_t)dv * 128 + s * 8);
        *(bf16x8*)(Sl + dv * 256 + ((s ^ (dv & 7)) << 4)) = vv;
      }
      __syncthreads();
      float sc = WA[((size_t)b * TSEQ + t0 + tl) * 32 + h * 4 + k];
#pragma unroll 1
      for (int ds = 0; ds < 4; ++ds) {
        bf16x8 qf = *(const bf16x8*)(Qb + qbase + (size_t)tl * 1024 + ds * 32 + lq * 8);
        bf16x8 qs;
#pragma unroll
        for (int e = 0; e < 8; ++e) qs[e] = (__bf16)((float)qf[e] * sc);
#pragma unroll
        for (int dvf = 0; dvf < 8; ++dvf) {
          int dv = dvf * 16 + l15;
          int slot = ds * 4 + lq;
          bf16x8 sf = *(const bf16x8*)(Sl + dv * 256 + ((slot ^ (dv & 7)) << 4));
          accO[dvf] = __builtin_amdgcn_mfma_f32_16x16x32_bf16(qs, sf, accO[dvf], 0, 0, 0);
        }
      }
    }
  }
#pragma unroll
  for (int dvf = 0; dvf < 8; ++dvf) {
    int dv = dvf * 16 + l15;
#pragma unroll
    for (int jj = 0; jj < 4; ++jj) {
      int tl = wbase + lq * 4 + jj;
      size_t off = ((size_t)b * TSEQ + t0 + tl) * 1024 + h * 128 + dv;
      Ob[off] = f2bf(accO[dvf][jj] + Olocal[off]);
    }
  }
}

// ------------- LayerNorm (two-pass, per row) -> f32 out -------------
__global__ __launch_bounds__(256) void ln_kernel(const float* __restrict__ Y,
    const float* __restrict__ g, const float* __restrict__ bta,
    float* __restrict__ out) {
  int row = blockIdx.x;
  int tid = threadIdx.x;
  int lane = tid & 63, wave = tid >> 6;
  __shared__ float red[8];
  const float* yr = Y + (size_t)row * 1024;
  float4 v = *(const float4*)(yr + tid * 4);
  float sum = v.x + v.y + v.z + v.w;
#pragma unroll
  for (int off = 32; off > 0; off >>= 1) sum += __shfl_down(sum, off);
  if (lane == 0) red[wave] = sum;
  __syncthreads();
  float mu = (red[0] + red[1] + red[2] + red[3]) * (1.f / 1024.f);
  float4 d;
  d.x = v.x - mu; d.y = v.y - mu; d.z = v.z - mu; d.w = v.w - mu;
  float sq = d.x * d.x + d.y * d.y + d.z * d.z + d.w * d.w;
#pragma unroll
  for (int off = 32; off > 0; off >>= 1) sq += __shfl_down(sq, off);
  __syncthreads();
  if (lane == 0) red[4 + wave] = sq;
  __syncthreads();
  float var = (red[4] + red[5] + red[6] + red[7]) * (1.f / 1024.f);
  float inv = rsqrtf(var + 1e-5f);
  float4 gg = *(const float4*)(g + tid * 4);
  float4 bb4 = *(const float4*)(bta + tid * 4);
  float4 o;
  o.x = d.x * inv * gg.x + bb4.x;
  o.y = d.y * inv * gg.y + bb4.y;
  o.z = d.z * inv * gg.z + bb4.z;
  o.w = d.w * inv * gg.w + bb4.w;
  *(float4*)(out + (size_t)row * 1024 + tid * 4) = o;
}

extern "C" void kernel_launch(void* const* d_in, const int* in_sizes, int n_in,
                              void* d_out, int out_size, void* d_ws, size_t ws_size,
                              hipStream_t stream) {
  const float* x    = (const float*)d_in[0];
  const float* mask = (const float*)d_in[1];
  const float* Wq   = (const float*)d_in[2];
  const float* Wk   = (const float*)d_in[3];
  const float* Wv   = (const float*)d_in[4];
  const float* Wb   = (const float*)d_in[5];
  const float* bb   = (const float*)d_in[6];
  const float* Wm   = (const float*)d_in[7];
  const float* bm   = (const float*)d_in[8];
  const float* Wo   = (const float*)d_in[9];
  const float* bo   = (const float*)d_in[10];
  const float* base_logit = (const float*)d_in[11];
  const float* ln_g = (const float*)d_in[12];
  const float* ln_b = (const float*)d_in[13];

  char* ws = (char*)d_ws;
  const size_t MB = 1024u * 1024u;
  unsigned short* Xb  = (unsigned short*)(ws + 0);
  unsigned short* Wtq = (unsigned short*)(ws + 8 * MB);
  unsigned short* Wtk = (unsigned short*)(ws + 10 * MB);
  unsigned short* Wtv = (unsigned short*)(ws + 12 * MB);
  unsigned short* Wto = (unsigned short*)(ws + 14 * MB);
  float* Rf  = (float*)(ws + 16 * MB);
  float* Wsf = (float*)(ws + 16 * MB + 512 * 1024);
  float* WAf = (float*)(ws + 17 * MB);
  float* IAf = (float*)(ws + 17 * MB + 512 * 1024);
  float* DUf = (float*)(ws + 18 * MB);
  float* ACf = (float*)(ws + 18 * MB + 512 * 1024);
  float* Wtf = (float*)(ws + 18 * MB + 768 * 1024);   // 160 KB (40x1024 f32)
  unsigned short* Qb = (unsigned short*)(ws + 19 * MB);
  unsigned short* Kb = (unsigned short*)(ws + 27 * MB);
  unsigned short* Vb = (unsigned short*)(ws + 35 * MB);
  float* Olocal = (float*)(ws + 43 * MB);
  unsigned short* Ob = (unsigned short*)(ws + 59 * MB);
  unsigned short* UTb = (unsigned short*)(ws + 67 * MB);
  unsigned short* S0T = (unsigned short*)(ws + 99 * MB);
  float* Yf = Olocal;
  if (ws_size < 131 * MB) return;

  cast_x_kernel<<<4096, 256, 0, stream>>>(x, Xb);
  dim3 tb(32, 8), tg(32, 32);
  transpose_w_kernel<<<tg, tb, 0, stream>>>(Wq, Wtq);
  transpose_w_kernel<<<tg, tb, 0, stream>>>(Wk, Wtk);
  transpose_w_kernel<<<tg, tb, 0, stream>>>(Wv, Wtv);
  transpose_w_kernel<<<tg, tb, 0, stream>>>(Wo, Wto);
  pack_wbm_kernel<<<160, 256, 0, stream>>>(Wb, Wm, Wtf);

  dim3 gg(8, 32);
  gemm128_kernel<1><<<gg, 256, 0, stream>>>(Xb, Wtq, Qb, nullptr, nullptr);
  gemm128_kernel<1><<<gg, 256, 0, stream>>>(Xb, Wtk, Kb, nullptr, nullptr);
  gemm128_kernel<0><<<gg, 256, 0, stream>>>(Xb, Wtv, Vb, nullptr, nullptr);

  rw2_kernel<<<4096, 256, 0, stream>>>(x, Wtf, bb, bm, base_logit, Rf, Wsf);
  decay2_kernel<<<256, 256, 0, stream>>>(Rf, Wsf, mask, WAf, IAf, DUf, ACf);

  chunkA_kernel<<<256, 512, 0, stream>>>(Qb, Kb, Vb, WAf, IAf, DUf, Olocal, UTb);
  chainB_kernel<<<4096, 256, 0, stream>>>(UTb, ACf, S0T);
  chunkC_kernel<<<256, 512, 0, stream>>>(Qb, S0T, WAf, Olocal, Ob);

  gemm128_kernel<2><<<gg, 256, 0, stream>>>(Ob, Wto, Yf, bo, x);

  ln_kernel<<<4096, 256, 0, stream>>>(Yf, ln_g, ln_b, (float*)d_out);
}

// Round 5
// 205.008 us; speedup vs baseline: 7.3297x; 1.0748x over previous
//
#include <hip/hip_runtime.h>
#include <hip/hip_bf16.h>
#include <math.h>

#define TSEQ 2048
#define NHID 1024

typedef float f32x4 __attribute__((ext_vector_type(4)));
typedef __bf16 bf16x8 __attribute__((ext_vector_type(8)));

static __device__ __forceinline__ unsigned short f2bf(float f) {
  unsigned u = __float_as_uint(f);
  u += 0x7fffu + ((u >> 16) & 1u);
  return (unsigned short)(u >> 16);
}
static __device__ __forceinline__ float bf2f(unsigned short h) {
  return __uint_as_float(((unsigned)h) << 16);
}

#define GLDS16(g, l) __builtin_amdgcn_global_load_lds( \
    (const __attribute__((address_space(1))) unsigned int*)(g), \
    (__attribute__((address_space(3))) unsigned int*)(l), 16, 0, 0)

// ---------------- cast x (f32) -> bf16 ----------------
__global__ __launch_bounds__(256) void cast_x_kernel(const float* __restrict__ X,
                                                     unsigned short* __restrict__ Xb) {
  int i = (blockIdx.x * 256 + threadIdx.x) * 4;
  float4 v = *(const float4*)(X + i);
  ushort4 o;
  o.x = f2bf(v.x); o.y = f2bf(v.y); o.z = f2bf(v.z); o.w = f2bf(v.w);
  *(ushort4*)(Xb + i) = o;
}

// ------------- transpose 1024x1024 f32 (K,N) -> bf16 (N,K) -------------
__global__ __launch_bounds__(256) void transpose_w_kernel(const float* __restrict__ W,
                                                          unsigned short* __restrict__ Wt) {
  __shared__ float tile[32][33];
  int bx = blockIdx.x * 32;
  int by = blockIdx.y * 32;
  int tx = threadIdx.x, ty = threadIdx.y;
#pragma unroll
  for (int i = 0; i < 32; i += 8)
    tile[ty + i][tx] = W[(size_t)(by + ty + i) * NHID + bx + tx];
  __syncthreads();
#pragma unroll
  for (int i = 0; i < 32; i += 8)
    Wt[(size_t)(bx + ty + i) * NHID + by + tx] = f2bf(tile[tx][ty + i]);
}

// ------------- bf16 MFMA GEMM with global_load_lds staging -------------
// A: bf16 [4096][1024]; Bt: bf16 [N][1024] (N-major, K contiguous)
// MODE 0: fused QKV (Bt has 3072 rows); cols 0-2047 get elu+1; bf16 out to Oq/Ok/Ov
// MODE 1: Wo: + bias[col] + res -> f32 Cf
template <int MODE>
__global__ __launch_bounds__(256) void gemm_glds_kernel(
    const unsigned short* __restrict__ A, const unsigned short* __restrict__ Bt,
    unsigned short* __restrict__ Oq, unsigned short* __restrict__ Ok,
    unsigned short* __restrict__ Ov, float* __restrict__ Cf,
    const float* __restrict__ bias, const float* __restrict__ res) {
  __shared__ __align__(16) unsigned short As[128 * 32];
  __shared__ __align__(16) unsigned short Bs[128 * 32];
  const int tid = threadIdx.x;
  const int lane = tid & 63;
  const int wave = tid >> 6;
  const int wr = wave >> 1, wc = wave & 1;
  const int rowBase = blockIdx.y * 128;
  const int colBase = blockIdx.x * 128;

  // staging chunks: c = wave*128 + i*64 + lane ; row=c>>2, slot=c&3
  // LDS is linear (dest = chunkbase + lane*16); global source pre-swizzled:
  // kc = slot ^ ((row>>1)&3) so that LDS slot s holds k-chunk s^((row>>1)&3).
  const int c0 = wave * 128 + lane;
  const int c1 = c0 + 64;
  const int r0 = c0 >> 2, kc0 = (c0 & 3) ^ ((r0 >> 1) & 3);
  const int r1 = c1 >> 2, kc1 = (c1 & 3) ^ ((r1 >> 1) & 3);
  const unsigned short* gA0 = A + (size_t)(rowBase + r0) * 1024 + kc0 * 8;
  const unsigned short* gA1 = A + (size_t)(rowBase + r1) * 1024 + kc1 * 8;
  const unsigned short* gB0 = Bt + (size_t)(colBase + r0) * 1024 + kc0 * 8;
  const unsigned short* gB1 = Bt + (size_t)(colBase + r1) * 1024 + kc1 * 8;
  unsigned short* lA0 = As + (size_t)(wave * 128) * 8;
  unsigned short* lA1 = As + (size_t)(wave * 128 + 64) * 8;
  unsigned short* lB0 = Bs + (size_t)(wave * 128) * 8;
  unsigned short* lB1 = Bs + (size_t)(wave * 128 + 64) * 8;

  const int kq = lane >> 4;
  const int r16 = lane & 15;

  f32x4 acc[4][4] = {};

  for (int k0 = 0; k0 < 1024; k0 += 32) {
    GLDS16(gA0 + k0, lA0);
    GLDS16(gA1 + k0, lA1);
    GLDS16(gB0 + k0, lB0);
    GLDS16(gB1 + k0, lB1);
    __syncthreads();   // vmcnt(0) drain before barrier -> LDS data visible
    bf16x8 af[4], bfr[4];
#pragma unroll
    for (int m = 0; m < 4; ++m) {
      int row = wr * 64 + m * 16 + r16;
      af[m] = *(const bf16x8*)(As + row * 32 + ((kq ^ ((row >> 1) & 3)) * 8));
      int colr = wc * 64 + m * 16 + r16;
      bfr[m] = *(const bf16x8*)(Bs + colr * 32 + ((kq ^ ((colr >> 1) & 3)) * 8));
    }
#pragma unroll
    for (int m = 0; m < 4; ++m)
#pragma unroll
      for (int n = 0; n < 4; ++n)
        acc[m][n] = __builtin_amdgcn_mfma_f32_16x16x32_bf16(af[m], bfr[n], acc[m][n], 0, 0, 0);
    __syncthreads();   // all frag reads done before next-tile DMA lands
  }

  const int r4 = (lane >> 4) * 4;
  if (MODE == 1) {
#pragma unroll
    for (int m = 0; m < 4; ++m)
#pragma unroll
      for (int n = 0; n < 4; ++n) {
        int col = colBase + wc * 64 + n * 16 + r16;
#pragma unroll
        for (int j = 0; j < 4; ++j) {
          int row = rowBase + wr * 64 + m * 16 + r4 + j;
          Cf[(size_t)row * 1024 + col] = acc[m][n][j] + bias[col] + res[(size_t)row * 1024 + col];
        }
      }
  } else {
    unsigned short* outp;
    int cb;
    bool elu;
    if (colBase < 1024)      { outp = Oq; cb = colBase;        elu = true;  }
    else if (colBase < 2048) { outp = Ok; cb = colBase - 1024; elu = true;  }
    else                     { outp = Ov; cb = colBase - 2048; elu = false; }
#pragma unroll
    for (int m = 0; m < 4; ++m)
#pragma unroll
      for (int n = 0; n < 4; ++n) {
        int col = cb + wc * 64 + n * 16 + r16;
#pragma unroll
        for (int j = 0; j < 4; ++j) {
          int row = rowBase + wr * 64 + m * 16 + r4 + j;
          float v = acc[m][n][j];
          if (elu) v = (v > 0.f) ? (v + 1.f) : expf(v);
          outp[(size_t)row * 1024 + col] = f2bf(v);
        }
      }
  }
}

// ------------- pack Wb (1024x8) | Wm (1024x32) -> Wt f32 [40][1024] -------------
__global__ __launch_bounds__(256) void pack_wbm_kernel(const float* __restrict__ Wb,
    const float* __restrict__ Wm, float* __restrict__ Wt) {
  int id = blockIdx.x * 256 + threadIdx.x;
  if (id >= 40960) return;
  int o = id >> 10, i = id & 1023;
  Wt[id] = (o < 8) ? Wb[i * 8 + o] : Wm[i * 32 + (o - 8)];
}

// ------------- per-(b,t): decay r_eff and softmax mix weights -------------
__global__ __launch_bounds__(256) void rw2_kernel(const float* __restrict__ x,
    const float* __restrict__ Wt, const float* __restrict__ bb,
    const float* __restrict__ bm, const float* __restrict__ base_logit,
    float* __restrict__ R, float* __restrict__ Wsm) {
  int row = blockIdx.x;
  __shared__ float xs[1024];
  __shared__ float outs[40];
  int tid = threadIdx.x;
  *(float4*)(xs + tid * 4) = *(const float4*)(x + (size_t)row * 1024 + tid * 4);
  __syncthreads();
  int wave = tid >> 6, lane = tid & 63;
  for (int o = wave; o < 40; o += 4) {
    const float* wr = Wt + o * 1024;
    float sum = 0.f;
#pragma unroll
    for (int it = 0; it < 16; ++it) {
      int i = it * 64 + lane;
      sum += xs[i] * wr[i];
    }
#pragma unroll
    for (int off = 32; off > 0; off >>= 1) sum += __shfl_down(sum, off);
    if (lane == 0) outs[o] = sum;
  }
  __syncthreads();
  if (tid < 32) {
    int h = tid >> 2;
    float beta = 1.f / (1.f + expf(-(outs[h] + bb[h])));
    float br = 1.f / (1.f + expf(-base_logit[tid]));
    float r = fminf(fmaxf(beta * br, 0.f), 0.999995f);
    float mval = outs[8 + tid] + bm[tid];
    float mx = fmaxf(mval, __shfl_xor(mval, 1));
    mx = fmaxf(mx, __shfl_xor(mx, 2));
    float ex = expf(mval - mx);
    float ssum = ex + __shfl_xor(ex, 1);
    ssum += __shfl_xor(ssum, 2);
    R[(size_t)row * 32 + tid] = r;
    Wsm[(size_t)row * 32 + tid] = ex / ssum;
  }
}

// ------------- decay precompute via wave product-scan -------------
__global__ __launch_bounds__(256) void decay2_kernel(const float* __restrict__ R,
    const float* __restrict__ Wsm, const float* __restrict__ mask,
    float* __restrict__ WA, float* __restrict__ IA, float* __restrict__ DU,
    float* __restrict__ AC) {
  int wave = threadIdx.x >> 6, lane = threadIdx.x & 63;
  int id = blockIdx.x * 4 + wave;
  int c = id & 15, k = (id >> 4) & 3, bh = id >> 6;
  int b = bh >> 3, h = bh & 7;
  int row0 = b * TSEQ + c * 128 + 2 * lane;
  float m0 = mask[row0], m1 = mask[row0 + 1];
  size_t i0 = (size_t)row0 * 32 + h * 4 + k;
  float rr0 = (m0 > 0.f) ? R[i0] : 1.f;
  float rr1 = (m1 > 0.f) ? R[i0 + 32] : 1.f;
  float incl = rr0 * rr1;
#pragma unroll
  for (int off = 1; off < 64; off <<= 1) {
    float o = __shfl_up(incl, off);
    if (lane >= off) incl *= o;
  }
  float excl = __shfl_up(incl, 1);
  if (lane == 0) excl = 1.f;
  float a0 = fmaxf(excl * rr0, 1e-25f);
  float a1 = fmaxf(a0 * rr1, 1e-25f);
  float aC = __shfl(a1, 63);
  if (lane == 63) AC[(bh * 16 + c) * 4 + k] = a1;
  bool v0 = m0 > 0.f, v1 = m1 > 0.f;
  float w0 = Wsm[i0], w1 = Wsm[i0 + 32];
  int dub = ((bh * 16 + c) * 4 + k) * 128 + 2 * lane;
  WA[i0] = v0 ? w0 * a0 : 0.f;
  WA[i0 + 32] = v1 ? w1 * a1 : 0.f;
  IA[i0] = v0 ? 1.f / a0 : 0.f;
  IA[i0 + 32] = v1 ? 1.f / a1 : 0.f;
  DU[dub] = v0 ? aC / a0 : 0.f;
  DU[dub + 1] = v1 ? aC / a1 : 0.f;
}

// ------------- kernel A: per (bh,chunk): local attention-form + U^T -------------
__global__ __launch_bounds__(512) void chunkA_kernel(
    const unsigned short* __restrict__ Qb, const unsigned short* __restrict__ Kb,
    const unsigned short* __restrict__ Vb,
    const float* __restrict__ WA, const float* __restrict__ IA,
    const float* __restrict__ DU,
    float* __restrict__ Olocal, unsigned short* __restrict__ UT) {
  __shared__ __align__(16) char KTl[32768];
  __shared__ __align__(16) char VTl[32768];
  __shared__ __align__(16) char Pl[32768];
  __shared__ __align__(16) float WAl[128][4];
  __shared__ __align__(16) float IAl[128][4];
  __shared__ float DUl[4][128];

  int wg = blockIdx.x;
  int bh = wg >> 4, c = wg & 15;
  int b = bh >> 3, h = bh & 7;
  int t0 = c * 128;
  int tid = threadIdx.x;
  int lane = tid & 63, wave = tid >> 6;
  int wbase = wave * 16;
  int l15 = lane & 15, lq = lane >> 4;

  const size_t qkvbase = ((size_t)b * TSEQ + t0) * 1024 + h * 128;

  for (int it = 0; it < 4; ++it) {
    int ci = tid + it * 512;
    int t = ci >> 4, s = ci & 15;
    bf16x8 kv = *(const bf16x8*)(Kb + qkvbase + (size_t)t * 1024 + s * 8);
    bf16x8 vv = *(const bf16x8*)(Vb + qkvbase + (size_t)t * 1024 + s * 8);
#pragma unroll
    for (int e = 0; e < 8; ++e) {
      int d = s * 8 + e;
      int off = d * 256 + (((t >> 3) ^ (d & 7)) << 4) + (t & 7) * 2;
      *(unsigned short*)(KTl + off) = f2bf((float)kv[e]);
      *(unsigned short*)(VTl + off) = f2bf((float)vv[e]);
    }
  }
  {
    int t = tid >> 2, k = tid & 3;
    size_t idx = ((size_t)b * TSEQ + t0 + t) * 32 + h * 4 + k;
    WAl[t][k] = WA[idx];
    IAl[t][k] = IA[idx];
    int k2 = tid >> 7, j = tid & 127;
    DUl[k2][j] = DU[((bh * 16 + c) * 4 + k2) * 128 + j];
  }
  __syncthreads();

  bf16x8 qf[4];
#pragma unroll
  for (int ds = 0; ds < 4; ++ds)
    qf[ds] = *(const bf16x8*)(Qb + qkvbase + (size_t)(wbase + l15) * 1024 + ds * 32 + lq * 8);
  f32x4 accP[8];
#pragma unroll
  for (int jf = 0; jf < 8; ++jf) {
    f32x4 a = {};
#pragma unroll
    for (int ds = 0; ds < 4; ++ds) {
      bf16x8 kfrag = *(const bf16x8*)(Kb + qkvbase + (size_t)(jf * 16 + l15) * 1024 + ds * 32 + lq * 8);
      a = __builtin_amdgcn_mfma_f32_16x16x32_bf16(qf[ds], kfrag, a, 0, 0, 0);
    }
    accP[jf] = a;
  }

  float4 wa4[4];
#pragma unroll
  for (int jj = 0; jj < 4; ++jj)
    wa4[jj] = *(const float4*)&WAl[wbase + lq * 4 + jj][0];
#pragma unroll
  for (int jf = 0; jf < 8; ++jf) {
    float4 ia4 = *(const float4*)&IAl[jf * 16 + l15][0];
#pragma unroll
    for (int jj = 0; jj < 4; ++jj) {
      int tl = wbase + lq * 4 + jj;
      int jl = jf * 16 + l15;
      float m = 0.f;
      if (jl <= tl)
        m = wa4[jj].x * ia4.x + wa4[jj].y * ia4.y + wa4[jj].z * ia4.z + wa4[jj].w * ia4.w;
      float pv = accP[jf][jj] * m;
      int off = tl * 256 + (((jl >> 3) ^ (tl & 7)) << 4) + (jl & 7) * 2;
      *(unsigned short*)(Pl + off) = f2bf(pv);
    }
  }

  bf16x8 pf[4];
#pragma unroll
  for (int js = 0; js < 4; ++js) {
    int tl = wbase + l15;
    int slot = js * 4 + lq;
    pf[js] = *(const bf16x8*)(Pl + tl * 256 + ((slot ^ (tl & 7)) << 4));
  }
#pragma unroll
  for (int dvf = 0; dvf < 8; ++dvf) {
    f32x4 a = {};
    int dv = dvf * 16 + l15;
#pragma unroll
    for (int js = 0; js < 4; ++js) {
      int slot = js * 4 + lq;
      bf16x8 vfrag = *(const bf16x8*)(VTl + dv * 256 + ((slot ^ (dv & 7)) << 4));
      a = __builtin_amdgcn_mfma_f32_16x16x32_bf16(pf[js], vfrag, a, 0, 0, 0);
    }
#pragma unroll
    for (int jj = 0; jj < 4; ++jj) {
      int tl = wbase + lq * 4 + jj;
      Olocal[((size_t)b * TSEQ + t0 + tl) * 1024 + h * 128 + dv] = a[jj];
    }
  }

  if (c < 15) {
#pragma unroll 1
    for (int k = 0; k < 4; ++k) {
      f32x4 accU[8] = {};
#pragma unroll 1
      for (int js = 0; js < 4; ++js) {
        int dvr = wbase + l15;
        int slot = js * 4 + lq;
        bf16x8 af = *(const bf16x8*)(VTl + dvr * 256 + ((slot ^ (dvr & 7)) << 4));
        int j0 = js * 32 + lq * 8;
        bf16x8 afs;
#pragma unroll
        for (int e = 0; e < 8; ++e)
          afs[e] = (__bf16)((float)af[e] * DUl[k][j0 + e]);
#pragma unroll
        for (int dkf = 0; dkf < 8; ++dkf) {
          int dk = dkf * 16 + l15;
          bf16x8 kf = *(const bf16x8*)(KTl + dk * 256 + ((slot ^ (dk & 7)) << 4));
          accU[dkf] = __builtin_amdgcn_mfma_f32_16x16x32_bf16(afs, kf, accU[dkf], 0, 0, 0);
        }
      }
      size_t ub = (((size_t)bh * 16 + c) * 4 + k) * 16384;
#pragma unroll
      for (int dkf = 0; dkf < 8; ++dkf) {
        int dk = dkf * 16 + l15;
#pragma unroll
        for (int jj = 0; jj < 4; ++jj) {
          int dvr = wbase + lq * 4 + jj;
          UT[ub + (size_t)dvr * 128 + dk] = f2bf(accU[dkf][jj]);
        }
      }
    }
  }
}

// ------------- kernel B: chain states S <- aC*S + U -------------
__global__ __launch_bounds__(256) void chainB_kernel(const unsigned short* __restrict__ UT,
    const float* __restrict__ AC, unsigned short* __restrict__ S0T) {
  int id = blockIdx.x * 256 + threadIdx.x;
  int dk = id & 127;
  int dv = (id >> 7) & 127;
  int k = (id >> 14) & 3;
  int bh = id >> 16;
  size_t elem = (size_t)dv * 128 + dk;
  float S = 0.f;
#pragma unroll 1
  for (int c = 0; c < 15; ++c) {
    size_t ub = (((size_t)bh * 16 + c) * 4 + k) * 16384;
    float u = bf2f(UT[ub + elem]);
    float aC = AC[(bh * 16 + c) * 4 + k];
    S = aC * S + u;
    size_t sb = (((size_t)bh * 16 + (c + 1)) * 4 + k) * 16384;
    S0T[sb + elem] = f2bf(S);
  }
}

// ------------- kernel C: cross-chunk O += sum_k diag(w*a) Q @ S0^k -------------
__global__ __launch_bounds__(512) void chunkC_kernel(const unsigned short* __restrict__ Qb,
    const unsigned short* __restrict__ S0T, const float* __restrict__ WA,
    const float* __restrict__ Olocal, unsigned short* __restrict__ Ob) {
  __shared__ __align__(16) char Sl[32768];
  int wg = blockIdx.x;
  int bh = wg >> 4, c = wg & 15;
  int b = bh >> 3, h = bh & 7;
  int t0 = c * 128;
  int tid = threadIdx.x, lane = tid & 63, wave = tid >> 6;
  int l15 = lane & 15, lq = lane >> 4, wbase = wave * 16;
  size_t qbase = ((size_t)b * TSEQ + t0) * 1024 + h * 128;

  f32x4 accO[8] = {};
  if (c > 0) {
    int tl = wbase + l15;
#pragma unroll 1
    for (int k = 0; k < 4; ++k) {
      __syncthreads();
      size_t sb = (((size_t)bh * 16 + c) * 4 + k) * 16384;
      for (int it = 0; it < 4; ++it) {
        int ci = tid + it * 512;
        int dv = ci >> 4, s = ci & 15;
        bf16x8 vv = *(const bf16x8*)(S0T + sb + (size_t)dv * 128 + s * 8);
        *(bf16x8*)(Sl + dv * 256 + ((s ^ (dv & 7)) << 4)) = vv;
      }
      __syncthreads();
      float sc = WA[((size_t)b * TSEQ + t0 + tl) * 32 + h * 4 + k];
#pragma unroll 1
      for (int ds = 0; ds < 4; ++ds) {
        bf16x8 qf = *(const bf16x8*)(Qb + qbase + (size_t)tl * 1024 + ds * 32 + lq * 8);
        bf16x8 qs;
#pragma unroll
        for (int e = 0; e < 8; ++e) qs[e] = (__bf16)((float)qf[e] * sc);
#pragma unroll
        for (int dvf = 0; dvf < 8; ++dvf) {
          int dv = dvf * 16 + l15;
          int slot = ds * 4 + lq;
          bf16x8 sf = *(const bf16x8*)(Sl + dv * 256 + ((slot ^ (dv & 7)) << 4));
          accO[dvf] = __builtin_amdgcn_mfma_f32_16x16x32_bf16(qs, sf, accO[dvf], 0, 0, 0);
        }
      }
    }
  }
#pragma unroll
  for (int dvf = 0; dvf < 8; ++dvf) {
    int dv = dvf * 16 + l15;
#pragma unroll
    for (int jj = 0; jj < 4; ++jj) {
      int tl = wbase + lq * 4 + jj;
      size_t off = ((size_t)b * TSEQ + t0 + tl) * 1024 + h * 128 + dv;
      Ob[off] = f2bf(accO[dvf][jj] + Olocal[off]);
    }
  }
}

// ------------- LayerNorm (two-pass, per row) -> f32 out -------------
__global__ __launch_bounds__(256) void ln_kernel(const float* __restrict__ Y,
    const float* __restrict__ g, const float* __restrict__ bta,
    float* __restrict__ out) {
  int row = blockIdx.x;
  int tid = threadIdx.x;
  int lane = tid & 63, wave = tid >> 6;
  __shared__ float red[8];
  const float* yr = Y + (size_t)row * 1024;
  float4 v = *(const float4*)(yr + tid * 4);
  float sum = v.x + v.y + v.z + v.w;
#pragma unroll
  for (int off = 32; off > 0; off >>= 1) sum += __shfl_down(sum, off);
  if (lane == 0) red[wave] = sum;
  __syncthreads();
  float mu = (red[0] + red[1] + red[2] + red[3]) * (1.f / 1024.f);
  float4 d;
  d.x = v.x - mu; d.y = v.y - mu; d.z = v.z - mu; d.w = v.w - mu;
  float sq = d.x * d.x + d.y * d.y + d.z * d.z + d.w * d.w;
#pragma unroll
  for (int off = 32; off > 0; off >>= 1) sq += __shfl_down(sq, off);
  __syncthreads();
  if (lane == 0) red[4 + wave] = sq;
  __syncthreads();
  float var = (red[4] + red[5] + red[6] + red[7]) * (1.f / 1024.f);
  float inv = rsqrtf(var + 1e-5f);
  float4 gg = *(const float4*)(g + tid * 4);
  float4 bb4 = *(const float4*)(bta + tid * 4);
  float4 o;
  o.x = d.x * inv * gg.x + bb4.x;
  o.y = d.y * inv * gg.y + bb4.y;
  o.z = d.z * inv * gg.z + bb4.z;
  o.w = d.w * inv * gg.w + bb4.w;
  *(float4*)(out + (size_t)row * 1024 + tid * 4) = o;
}

extern "C" void kernel_launch(void* const* d_in, const int* in_sizes, int n_in,
                              void* d_out, int out_size, void* d_ws, size_t ws_size,
                              hipStream_t stream) {
  const float* x    = (const float*)d_in[0];
  const float* mask = (const float*)d_in[1];
  const float* Wq   = (const float*)d_in[2];
  const float* Wk   = (const float*)d_in[3];
  const float* Wv   = (const float*)d_in[4];
  const float* Wb   = (const float*)d_in[5];
  const float* bb   = (const float*)d_in[6];
  const float* Wm   = (const float*)d_in[7];
  const float* bm   = (const float*)d_in[8];
  const float* Wo   = (const float*)d_in[9];
  const float* bo   = (const float*)d_in[10];
  const float* base_logit = (const float*)d_in[11];
  const float* ln_g = (const float*)d_in[12];
  const float* ln_b = (const float*)d_in[13];

  char* ws = (char*)d_ws;
  const size_t MB = 1024u * 1024u;
  unsigned short* Xb    = (unsigned short*)(ws + 0);
  unsigned short* Wqkvt = (unsigned short*)(ws + 8 * MB);   // [3072][1024] bf16
  unsigned short* Wto   = (unsigned short*)(ws + 14 * MB);
  float* Rf  = (float*)(ws + 16 * MB);
  float* Wsf = (float*)(ws + 16 * MB + 512 * 1024);
  float* WAf = (float*)(ws + 17 * MB);
  float* IAf = (float*)(ws + 17 * MB + 512 * 1024);
  float* DUf = (float*)(ws + 18 * MB);
  float* ACf = (float*)(ws + 18 * MB + 512 * 1024);
  float* Wtf = (float*)(ws + 18 * MB + 768 * 1024);
  unsigned short* Qb = (unsigned short*)(ws + 19 * MB);
  unsigned short* Kb = (unsigned short*)(ws + 27 * MB);
  unsigned short* Vb = (unsigned short*)(ws + 35 * MB);
  float* Olocal = (float*)(ws + 43 * MB);
  unsigned short* Ob = (unsigned short*)(ws + 59 * MB);
  unsigned short* UTb = (unsigned short*)(ws + 67 * MB);
  unsigned short* S0T = (unsigned short*)(ws + 99 * MB);
  float* Yf = Olocal;
  if (ws_size < 131 * MB) return;

  cast_x_kernel<<<4096, 256, 0, stream>>>(x, Xb);
  dim3 tb(32, 8), tg(32, 32);
  transpose_w_kernel<<<tg, tb, 0, stream>>>(Wq, Wqkvt);
  transpose_w_kernel<<<tg, tb, 0, stream>>>(Wk, Wqkvt + 1024 * 1024);
  transpose_w_kernel<<<tg, tb, 0, stream>>>(Wv, Wqkvt + 2 * 1024 * 1024);
  transpose_w_kernel<<<tg, tb, 0, stream>>>(Wo, Wto);
  pack_wbm_kernel<<<160, 256, 0, stream>>>(Wb, Wm, Wtf);

  dim3 gqkv(24, 32);
  gemm_glds_kernel<0><<<gqkv, 256, 0, stream>>>(Xb, Wqkvt, Qb, Kb, Vb, nullptr, nullptr, nullptr);

  rw2_kernel<<<4096, 256, 0, stream>>>(x, Wtf, bb, bm, base_logit, Rf, Wsf);
  decay2_kernel<<<256, 256, 0, stream>>>(Rf, Wsf, mask, WAf, IAf, DUf, ACf);

  chunkA_kernel<<<256, 512, 0, stream>>>(Qb, Kb, Vb, WAf, IAf, DUf, Olocal, UTb);
  chainB_kernel<<<4096, 256, 0, stream>>>(UTb, ACf, S0T);
  chunkC_kernel<<<256, 512, 0, stream>>>(Qb, S0T, WAf, Olocal, Ob);

  dim3 gwo(8, 32);
  gemm_glds_kernel<1><<<gwo, 256, 0, stream>>>(Ob, Wto, nullptr, nullptr, nullptr, Yf, bo, x);

  ln_kernel<<<4096, 256, 0, stream>>>(Yf, ln_g, ln_b, (float*)d_out);
}

// Round 6
// 197.815 us; speedup vs baseline: 7.5963x; 1.0364x over previous
//
#include <hip/hip_runtime.h>
#include <hip/hip_bf16.h>
#include <math.h>

#define TSEQ 2048
#define NHID 1024

typedef float f32x4 __attribute__((ext_vector_type(4)));
typedef __bf16 bf16x8 __attribute__((ext_vector_type(8)));

static __device__ __forceinline__ unsigned short f2bf(float f) {
  unsigned u = __float_as_uint(f);
  u += 0x7fffu + ((u >> 16) & 1u);
  return (unsigned short)(u >> 16);
}
static __device__ __forceinline__ float bf2f(unsigned short h) {
  return __uint_as_float(((unsigned)h) << 16);
}

#define GLDS16(g, l) __builtin_amdgcn_global_load_lds( \
    (const __attribute__((address_space(1))) unsigned int*)(g), \
    (__attribute__((address_space(3))) unsigned int*)(l), 16, 0, 0)

// ---------------- cast x (f32) -> bf16 ----------------
__global__ __launch_bounds__(256) void cast_x_kernel(const float* __restrict__ X,
                                                     unsigned short* __restrict__ Xb) {
  int i = (blockIdx.x * 256 + threadIdx.x) * 4;
  float4 v = *(const float4*)(X + i);
  ushort4 o;
  o.x = f2bf(v.x); o.y = f2bf(v.y); o.z = f2bf(v.z); o.w = f2bf(v.w);
  *(ushort4*)(Xb + i) = o;
}

// ------------- transpose 1024x1024 f32 (K,N) -> bf16 (N,K) -------------
__global__ __launch_bounds__(256) void transpose_w_kernel(const float* __restrict__ W,
                                                          unsigned short* __restrict__ Wt) {
  __shared__ float tile[32][33];
  int bx = blockIdx.x * 32;
  int by = blockIdx.y * 32;
  int tx = threadIdx.x, ty = threadIdx.y;
#pragma unroll
  for (int i = 0; i < 32; i += 8)
    tile[ty + i][tx] = W[(size_t)(by + ty + i) * NHID + bx + tx];
  __syncthreads();
#pragma unroll
  for (int i = 0; i < 32; i += 8)
    Wt[(size_t)(bx + ty + i) * NHID + by + tx] = f2bf(tile[tx][ty + i]);
}

// ------------- bf16 MFMA GEMM, double-buffered LDS + counted vmcnt -------------
// A: bf16 [4096][1024]; Bt: bf16 [N][1024] (N-major, K contiguous)
// MODE 0: fused QKV (Bt 3072 rows); cols<2048 get elu+1; bf16 out Oq/Ok/Ov
// MODE 1: Wo: + bias[col] + res -> f32 Cf
template <int MODE>
__global__ __launch_bounds__(256) void gemm_pipe_kernel(
    const unsigned short* __restrict__ A, const unsigned short* __restrict__ Bt,
    unsigned short* __restrict__ Oq, unsigned short* __restrict__ Ok,
    unsigned short* __restrict__ Ov, float* __restrict__ Cf,
    const float* __restrict__ bias, const float* __restrict__ res) {
  __shared__ __align__(16) unsigned short As[2][4096];
  __shared__ __align__(16) unsigned short Bs[2][4096];
  const int tid = threadIdx.x;
  const int lane = tid & 63;
  const int wave = tid >> 6;
  const int wr = wave >> 1, wc = wave & 1;
  const int rowBase = blockIdx.y * 128;
  const int colBase = blockIdx.x * 128;

  // staging chunks: c = wave*128 + {lane, lane+64}; row=c>>2; LDS byte off = c*16
  // global k-chunk pre-swizzled: kc = (c&3) ^ ((row>>1)&3)
  const int c0 = wave * 128 + lane;
  const int c1 = c0 + 64;
  const int r0 = c0 >> 2, kc0 = (c0 & 3) ^ ((r0 >> 1) & 3);
  const int r1 = c1 >> 2, kc1 = (c1 & 3) ^ ((r1 >> 1) & 3);
  const unsigned short* gA0 = A + (size_t)(rowBase + r0) * 1024 + kc0 * 8;
  const unsigned short* gA1 = A + (size_t)(rowBase + r1) * 1024 + kc1 * 8;
  const unsigned short* gB0 = Bt + (size_t)(colBase + r0) * 1024 + kc0 * 8;
  const unsigned short* gB1 = Bt + (size_t)(colBase + r1) * 1024 + kc1 * 8;
  const int wofs = wave * 1024;   // shorts; +512 for the second chunk-group

  const int kq = lane >> 4;
  const int r16 = lane & 15;

  f32x4 acc[4][4] = {};

#define STAGE(buf, k0)                                   \
  do {                                                   \
    GLDS16(gA0 + (k0), &As[buf][wofs]);                  \
    GLDS16(gA1 + (k0), &As[buf][wofs + 512]);            \
    GLDS16(gB0 + (k0), &Bs[buf][wofs]);                  \
    GLDS16(gB1 + (k0), &Bs[buf][wofs + 512]);            \
  } while (0)

  STAGE(0, 0);
  for (int t = 0; t < 32; ++t) {
    const int cur = t & 1;
    if (t < 31) {
      STAGE(cur ^ 1, (t + 1) * 32);
      asm volatile("s_waitcnt vmcnt(4)" ::: "memory");
    } else {
      asm volatile("s_waitcnt vmcnt(0)" ::: "memory");
    }
    __builtin_amdgcn_s_barrier();
    asm volatile("" ::: "memory");
    bf16x8 af[4], bfr[4];
#pragma unroll
    for (int m = 0; m < 4; ++m) {
      int row = wr * 64 + m * 16 + r16;
      af[m] = *(const bf16x8*)(&As[cur][row * 32 + (kq ^ ((row >> 1) & 3)) * 8]);
      int colr = wc * 64 + m * 16 + r16;
      bfr[m] = *(const bf16x8*)(&Bs[cur][colr * 32 + (kq ^ ((colr >> 1) & 3)) * 8]);
    }
    __builtin_amdgcn_s_setprio(1);
#pragma unroll
    for (int m = 0; m < 4; ++m)
#pragma unroll
      for (int n = 0; n < 4; ++n)
        acc[m][n] = __builtin_amdgcn_mfma_f32_16x16x32_bf16(af[m], bfr[n], acc[m][n], 0, 0, 0);
    __builtin_amdgcn_s_setprio(0);
    asm volatile("" ::: "memory");
    __builtin_amdgcn_s_barrier();
    asm volatile("" ::: "memory");
  }
#undef STAGE

  const int r4 = (lane >> 4) * 4;
  if (MODE == 1) {
#pragma unroll
    for (int m = 0; m < 4; ++m)
#pragma unroll
      for (int n = 0; n < 4; ++n) {
        int col = colBase + wc * 64 + n * 16 + r16;
#pragma unroll
        for (int j = 0; j < 4; ++j) {
          int row = rowBase + wr * 64 + m * 16 + r4 + j;
          Cf[(size_t)row * 1024 + col] = acc[m][n][j] + bias[col] + res[(size_t)row * 1024 + col];
        }
      }
  } else {
    unsigned short* outp;
    int cb;
    bool elu;
    if (colBase < 1024)      { outp = Oq; cb = colBase;        elu = true;  }
    else if (colBase < 2048) { outp = Ok; cb = colBase - 1024; elu = true;  }
    else                     { outp = Ov; cb = colBase - 2048; elu = false; }
#pragma unroll
    for (int m = 0; m < 4; ++m)
#pragma unroll
      for (int n = 0; n < 4; ++n) {
        int col = cb + wc * 64 + n * 16 + r16;
#pragma unroll
        for (int j = 0; j < 4; ++j) {
          int row = rowBase + wr * 64 + m * 16 + r4 + j;
          float v = acc[m][n][j];
          if (elu) v = (v > 0.f) ? (v + 1.f) : expf(v);
          outp[(size_t)row * 1024 + col] = f2bf(v);
        }
      }
  }
}

// ------------- pack Wb (1024x8) | Wm (1024x32) -> Wt f32 [40][1024] -------------
__global__ __launch_bounds__(256) void pack_wbm_kernel(const float* __restrict__ Wb,
    const float* __restrict__ Wm, float* __restrict__ Wt) {
  int id = blockIdx.x * 256 + threadIdx.x;
  if (id >= 40960) return;
  int o = id >> 10, i = id & 1023;
  Wt[id] = (o < 8) ? Wb[i * 8 + o] : Wm[i * 32 + (o - 8)];
}

// ------------- per-(b,t): decay r_eff and softmax mix weights -------------
__global__ __launch_bounds__(256) void rw2_kernel(const float* __restrict__ x,
    const float* __restrict__ Wt, const float* __restrict__ bb,
    const float* __restrict__ bm, const float* __restrict__ base_logit,
    float* __restrict__ R, float* __restrict__ Wsm) {
  int row = blockIdx.x;
  __shared__ float xs[1024];
  __shared__ float outs[40];
  int tid = threadIdx.x;
  *(float4*)(xs + tid * 4) = *(const float4*)(x + (size_t)row * 1024 + tid * 4);
  __syncthreads();
  int wave = tid >> 6, lane = tid & 63;
  for (int o = wave; o < 40; o += 4) {
    const float* wr = Wt + o * 1024;
    float sum = 0.f;
#pragma unroll
    for (int it = 0; it < 16; ++it) {
      int i = it * 64 + lane;
      sum += xs[i] * wr[i];
    }
#pragma unroll
    for (int off = 32; off > 0; off >>= 1) sum += __shfl_down(sum, off);
    if (lane == 0) outs[o] = sum;
  }
  __syncthreads();
  if (tid < 32) {
    int h = tid >> 2;
    float beta = 1.f / (1.f + expf(-(outs[h] + bb[h])));
    float br = 1.f / (1.f + expf(-base_logit[tid]));
    float r = fminf(fmaxf(beta * br, 0.f), 0.999995f);
    float mval = outs[8 + tid] + bm[tid];
    float mx = fmaxf(mval, __shfl_xor(mval, 1));
    mx = fmaxf(mx, __shfl_xor(mx, 2));
    float ex = expf(mval - mx);
    float ssum = ex + __shfl_xor(ex, 1);
    ssum += __shfl_xor(ssum, 2);
    R[(size_t)row * 32 + tid] = r;
    Wsm[(size_t)row * 32 + tid] = ex / ssum;
  }
}

// ------------- decay precompute via wave product-scan -------------
__global__ __launch_bounds__(256) void decay2_kernel(const float* __restrict__ R,
    const float* __restrict__ Wsm, const float* __restrict__ mask,
    float* __restrict__ WA, float* __restrict__ IA, float* __restrict__ DU,
    float* __restrict__ AC) {
  int wave = threadIdx.x >> 6, lane = threadIdx.x & 63;
  int id = blockIdx.x * 4 + wave;
  int c = id & 15, k = (id >> 4) & 3, bh = id >> 6;
  int b = bh >> 3, h = bh & 7;
  int row0 = b * TSEQ + c * 128 + 2 * lane;
  float m0 = mask[row0], m1 = mask[row0 + 1];
  size_t i0 = (size_t)row0 * 32 + h * 4 + k;
  float rr0 = (m0 > 0.f) ? R[i0] : 1.f;
  float rr1 = (m1 > 0.f) ? R[i0 + 32] : 1.f;
  float incl = rr0 * rr1;
#pragma unroll
  for (int off = 1; off < 64; off <<= 1) {
    float o = __shfl_up(incl, off);
    if (lane >= off) incl *= o;
  }
  float excl = __shfl_up(incl, 1);
  if (lane == 0) excl = 1.f;
  float a0 = fmaxf(excl * rr0, 1e-25f);
  float a1 = fmaxf(a0 * rr1, 1e-25f);
  float aC = __shfl(a1, 63);
  if (lane == 63) AC[(bh * 16 + c) * 4 + k] = a1;
  bool v0 = m0 > 0.f, v1 = m1 > 0.f;
  float w0 = Wsm[i0], w1 = Wsm[i0 + 32];
  int dub = ((bh * 16 + c) * 4 + k) * 128 + 2 * lane;
  WA[i0] = v0 ? w0 * a0 : 0.f;
  WA[i0 + 32] = v1 ? w1 * a1 : 0.f;
  IA[i0] = v0 ? 1.f / a0 : 0.f;
  IA[i0 + 32] = v1 ? 1.f / a1 : 0.f;
  DU[dub] = v0 ? aC / a0 : 0.f;
  DU[dub + 1] = v1 ? aC / a1 : 0.f;
}

// ------------- kernel A: per (bh,chunk): local attention-form + U^T -------------
__global__ __launch_bounds__(512) void chunkA_kernel(
    const unsigned short* __restrict__ Qb, const unsigned short* __restrict__ Kb,
    const unsigned short* __restrict__ Vb,
    const float* __restrict__ WA, const float* __restrict__ IA,
    const float* __restrict__ DU,
    float* __restrict__ Olocal, unsigned short* __restrict__ UT) {
  __shared__ __align__(16) char KTl[32768];
  __shared__ __align__(16) char VTl[32768];
  __shared__ __align__(16) char Pl[32768];
  __shared__ __align__(16) float WAl[128][4];
  __shared__ __align__(16) float IAl[128][4];
  __shared__ float DUl[4][128];

  int wg = blockIdx.x;
  int bh = wg >> 4, c = wg & 15;
  int b = bh >> 3, h = bh & 7;
  int t0 = c * 128;
  int tid = threadIdx.x;
  int lane = tid & 63, wave = tid >> 6;
  int wbase = wave * 16;
  int l15 = lane & 15, lq = lane >> 4;

  const size_t qkvbase = ((size_t)b * TSEQ + t0) * 1024 + h * 128;

  for (int it = 0; it < 4; ++it) {
    int ci = tid + it * 512;
    int t = ci >> 4, s = ci & 15;
    bf16x8 kv = *(const bf16x8*)(Kb + qkvbase + (size_t)t * 1024 + s * 8);
    bf16x8 vv = *(const bf16x8*)(Vb + qkvbase + (size_t)t * 1024 + s * 8);
#pragma unroll
    for (int e = 0; e < 8; ++e) {
      int d = s * 8 + e;
      int off = d * 256 + (((t >> 3) ^ (d & 7)) << 4) + (t & 7) * 2;
      *(unsigned short*)(KTl + off) = f2bf((float)kv[e]);
      *(unsigned short*)(VTl + off) = f2bf((float)vv[e]);
    }
  }
  {
    int t = tid >> 2, k = tid & 3;
    size_t idx = ((size_t)b * TSEQ + t0 + t) * 32 + h * 4 + k;
    WAl[t][k] = WA[idx];
    IAl[t][k] = IA[idx];
    int k2 = tid >> 7, j = tid & 127;
    DUl[k2][j] = DU[((bh * 16 + c) * 4 + k2) * 128 + j];
  }
  __syncthreads();

  bf16x8 qf[4];
#pragma unroll
  for (int ds = 0; ds < 4; ++ds)
    qf[ds] = *(const bf16x8*)(Qb + qkvbase + (size_t)(wbase + l15) * 1024 + ds * 32 + lq * 8);
  f32x4 accP[8];
#pragma unroll
  for (int jf = 0; jf < 8; ++jf) {
    f32x4 a = {};
#pragma unroll
    for (int ds = 0; ds < 4; ++ds) {
      bf16x8 kfrag = *(const bf16x8*)(Kb + qkvbase + (size_t)(jf * 16 + l15) * 1024 + ds * 32 + lq * 8);
      a = __builtin_amdgcn_mfma_f32_16x16x32_bf16(qf[ds], kfrag, a, 0, 0, 0);
    }
    accP[jf] = a;
  }

  float4 wa4[4];
#pragma unroll
  for (int jj = 0; jj < 4; ++jj)
    wa4[jj] = *(const float4*)&WAl[wbase + lq * 4 + jj][0];
#pragma unroll
  for (int jf = 0; jf < 8; ++jf) {
    float4 ia4 = *(const float4*)&IAl[jf * 16 + l15][0];
#pragma unroll
    for (int jj = 0; jj < 4; ++jj) {
      int tl = wbase + lq * 4 + jj;
      int jl = jf * 16 + l15;
      float m = 0.f;
      if (jl <= tl)
        m = wa4[jj].x * ia4.x + wa4[jj].y * ia4.y + wa4[jj].z * ia4.z + wa4[jj].w * ia4.w;
      float pv = accP[jf][jj] * m;
      int off = tl * 256 + (((jl >> 3) ^ (tl & 7)) << 4) + (jl & 7) * 2;
      *(unsigned short*)(Pl + off) = f2bf(pv);
    }
  }

  bf16x8 pf[4];
#pragma unroll
  for (int js = 0; js < 4; ++js) {
    int tl = wbase + l15;
    int slot = js * 4 + lq;
    pf[js] = *(const bf16x8*)(Pl + tl * 256 + ((slot ^ (tl & 7)) << 4));
  }
#pragma unroll
  for (int dvf = 0; dvf < 8; ++dvf) {
    f32x4 a = {};
    int dv = dvf * 16 + l15;
#pragma unroll
    for (int js = 0; js < 4; ++js) {
      int slot = js * 4 + lq;
      bf16x8 vfrag = *(const bf16x8*)(VTl + dv * 256 + ((slot ^ (dv & 7)) << 4));
      a = __builtin_amdgcn_mfma_f32_16x16x32_bf16(pf[js], vfrag, a, 0, 0, 0);
    }
#pragma unroll
    for (int jj = 0; jj < 4; ++jj) {
      int tl = wbase + lq * 4 + jj;
      Olocal[((size_t)b * TSEQ + t0 + tl) * 1024 + h * 128 + dv] = a[jj];
    }
  }

  if (c < 15) {
#pragma unroll 1
    for (int k = 0; k < 4; ++k) {
      f32x4 accU[8] = {};
#pragma unroll 1
      for (int js = 0; js < 4; ++js) {
        int dvr = wbase + l15;
        int slot = js * 4 + lq;
        bf16x8 af = *(const bf16x8*)(VTl + dvr * 256 + ((slot ^ (dvr & 7)) << 4));
        int j0 = js * 32 + lq * 8;
        bf16x8 afs;
#pragma unroll
        for (int e = 0; e < 8; ++e)
          afs[e] = (__bf16)((float)af[e] * DUl[k][j0 + e]);
#pragma unroll
        for (int dkf = 0; dkf < 8; ++dkf) {
          int dk = dkf * 16 + l15;
          bf16x8 kf = *(const bf16x8*)(KTl + dk * 256 + ((slot ^ (dk & 7)) << 4));
          accU[dkf] = __builtin_amdgcn_mfma_f32_16x16x32_bf16(afs, kf, accU[dkf], 0, 0, 0);
        }
      }
      size_t ub = (((size_t)bh * 16 + c) * 4 + k) * 16384;
#pragma unroll
      for (int dkf = 0; dkf < 8; ++dkf) {
        int dk = dkf * 16 + l15;
#pragma unroll
        for (int jj = 0; jj < 4; ++jj) {
          int dvr = wbase + lq * 4 + jj;
          UT[ub + (size_t)dvr * 128 + dk] = f2bf(accU[dkf][jj]);
        }
      }
    }
  }
}

// ------------- kernel B: chain states S <- aC*S + U -------------
__global__ __launch_bounds__(256) void chainB_kernel(const unsigned short* __restrict__ UT,
    const float* __restrict__ AC, unsigned short* __restrict__ S0T) {
  int id = blockIdx.x * 256 + threadIdx.x;
  int dk = id & 127;
  int dv = (id >> 7) & 127;
  int k = (id >> 14) & 3;
  int bh = id >> 16;
  size_t elem = (size_t)dv * 128 + dk;
  float S = 0.f;
#pragma unroll 1
  for (int c = 0; c < 15; ++c) {
    size_t ub = (((size_t)bh * 16 + c) * 4 + k) * 16384;
    float u = bf2f(UT[ub + elem]);
    float aC = AC[(bh * 16 + c) * 4 + k];
    S = aC * S + u;
    size_t sb = (((size_t)bh * 16 + (c + 1)) * 4 + k) * 16384;
    S0T[sb + elem] = f2bf(S);
  }
}

// ------------- kernel C: cross-chunk O += sum_k diag(w*a) Q @ S0^k -------------
__global__ __launch_bounds__(512) void chunkC_kernel(const unsigned short* __restrict__ Qb,
    const unsigned short* __restrict__ S0T, const float* __restrict__ WA,
    const float* __restrict__ Olocal, unsigned short* __restrict__ Ob) {
  __shared__ __align__(16) char Sl[32768];
  int wg = blockIdx.x;
  int bh = wg >> 4, c = wg & 15;
  int b = bh >> 3, h = bh & 7;
  int t0 = c * 128;
  int tid = threadIdx.x, lane = tid & 63, wave = tid >> 6;
  int l15 = lane & 15, lq = lane >> 4, wbase = wave * 16;
  size_t qbase = ((size_t)b * TSEQ + t0) * 1024 + h * 128;

  f32x4 accO[8] = {};
  if (c > 0) {
    int tl = wbase + l15;
#pragma unroll 1
    for (int k = 0; k < 4; ++k) {
      __syncthreads();
      size_t sb = (((size_t)bh * 16 + c) * 4 + k) * 16384;
      for (int it = 0; it < 4; ++it) {
        int ci = tid + it * 512;
        int dv = ci >> 4, s = ci & 15;
        bf16x8 vv = *(const bf16x8*)(S0T + sb + (size_t)dv * 128 + s * 8);
        *(bf16x8*)(Sl + dv * 256 + ((s ^ (dv & 7)) << 4)) = vv;
      }
      __syncthreads();
      float sc = WA[((size_t)b * TSEQ + t0 + tl) * 32 + h * 4 + k];
#pragma unroll 1
      for (int ds = 0; ds < 4; ++ds) {
        bf16x8 qf = *(const bf16x8*)(Qb + qbase + (size_t)tl * 1024 + ds * 32 + lq * 8);
        bf16x8 qs;
#pragma unroll
        for (int e = 0; e < 8; ++e) qs[e] = (__bf16)((float)qf[e] * sc);
#pragma unroll
        for (int dvf = 0; dvf < 8; ++dvf) {
          int dv = dvf * 16 + l15;
          int slot = ds * 4 + lq;
          bf16x8 sf = *(const bf16x8*)(Sl + dv * 256 + ((slot ^ (dv & 7)) << 4));
          accO[dvf] = __builtin_amdgcn_mfma_f32_16x16x32_bf16(qs, sf, accO[dvf], 0, 0, 0);
        }
      }
    }
  }
#pragma unroll
  for (int dvf = 0; dvf < 8; ++dvf) {
    int dv = dvf * 16 + l15;
#pragma unroll
    for (int jj = 0; jj < 4; ++jj) {
      int tl = wbase + lq * 4 + jj;
      size_t off = ((size_t)b * TSEQ + t0 + tl) * 1024 + h * 128 + dv;
      Ob[off] = f2bf(accO[dvf][jj] + Olocal[off]);
    }
  }
}

// ------------- LayerNorm (two-pass, per row) -> f32 out -------------
__global__ __launch_bounds__(256) void ln_kernel(const float* __restrict__ Y,
    const float* __restrict__ g, const float* __restrict__ bta,
    float* __restrict__ out) {
  int row = blockIdx.x;
  int tid = threadIdx.x;
  int lane = tid & 63, wave = tid >> 6;
  __shared__ float red[8];
  const float* yr = Y + (size_t)row * 1024;
  float4 v = *(const float4*)(yr + tid * 4);
  float sum = v.x + v.y + v.z + v.w;
#pragma unroll
  for (int off = 32; off > 0; off >>= 1) sum += __shfl_down(sum, off);
  if (lane == 0) red[wave] = sum;
  __syncthreads();
  float mu = (red[0] + red[1] + red[2] + red[3]) * (1.f / 1024.f);
  float4 d;
  d.x = v.x - mu; d.y = v.y - mu; d.z = v.z - mu; d.w = v.w - mu;
  float sq = d.x * d.x + d.y * d.y + d.z * d.z + d.w * d.w;
#pragma unroll
  for (int off = 32; off > 0; off >>= 1) sq += __shfl_down(sq, off);
  __syncthreads();
  if (lane == 0) red[4 + wave] = sq;
  __syncthreads();
  float var = (red[4] + red[5] + red[6] + red[7]) * (1.f / 1024.f);
  float inv = rsqrtf(var + 1e-5f);
  float4 gg = *(const float4*)(g + tid * 4);
  float4 bb4 = *(const float4*)(bta + tid * 4);
  float4 o;
  o.x = d.x * inv * gg.x + bb4.x;
  o.y = d.y * inv * gg.y + bb4.y;
  o.z = d.z * inv * gg.z + bb4.z;
  o.w = d.w * inv * gg.w + bb4.w;
  *(float4*)(out + (size_t)row * 1024 + tid * 4) = o;
}

extern "C" void kernel_launch(void* const* d_in, const int* in_sizes, int n_in,
                              void* d_out, int out_size, void* d_ws, size_t ws_size,
                              hipStream_t stream) {
  const float* x    = (const float*)d_in[0];
  const float* mask = (const float*)d_in[1];
  const float* Wq   = (const float*)d_in[2];
  const float* Wk   = (const float*)d_in[3];
  const float* Wv   = (const float*)d_in[4];
  const float* Wb   = (const float*)d_in[5];
  const float* bb   = (const float*)d_in[6];
  const float* Wm   = (const float*)d_in[7];
  const float* bm   = (const float*)d_in[8];
  const float* Wo   = (const float*)d_in[9];
  const float* bo   = (const float*)d_in[10];
  const float* base_logit = (const float*)d_in[11];
  const float* ln_g = (const float*)d_in[12];
  const float* ln_b = (const float*)d_in[13];

  char* ws = (char*)d_ws;
  const size_t MB = 1024u * 1024u;
  unsigned short* Xb    = (unsigned short*)(ws + 0);
  unsigned short* Wqkvt = (unsigned short*)(ws + 8 * MB);   // [3072][1024] bf16
  unsigned short* Wto   = (unsigned short*)(ws + 14 * MB);
  float* Rf  = (float*)(ws + 16 * MB);
  float* Wsf = (float*)(ws + 16 * MB + 512 * 1024);
  float* WAf = (float*)(ws + 17 * MB);
  float* IAf = (float*)(ws + 17 * MB + 512 * 1024);
  float* DUf = (float*)(ws + 18 * MB);
  float* ACf = (float*)(ws + 18 * MB + 512 * 1024);
  float* Wtf = (float*)(ws + 18 * MB + 768 * 1024);
  unsigned short* Qb = (unsigned short*)(ws + 19 * MB);
  unsigned short* Kb = (unsigned short*)(ws + 27 * MB);
  unsigned short* Vb = (unsigned short*)(ws + 35 * MB);
  float* Olocal = (float*)(ws + 43 * MB);
  unsigned short* Ob = (unsigned short*)(ws + 59 * MB);
  unsigned short* UTb = (unsigned short*)(ws + 67 * MB);
  unsigned short* S0T = (unsigned short*)(ws + 99 * MB);
  float* Yf = Olocal;
  if (ws_size < 131 * MB) return;

  cast_x_kernel<<<4096, 256, 0, stream>>>(x, Xb);
  dim3 tb(32, 8), tg(32, 32);
  transpose_w_kernel<<<tg, tb, 0, stream>>>(Wq, Wqkvt);
  transpose_w_kernel<<<tg, tb, 0, stream>>>(Wk, Wqkvt + 1024 * 1024);
  transpose_w_kernel<<<tg, tb, 0, stream>>>(Wv, Wqkvt + 2 * 1024 * 1024);
  transpose_w_kernel<<<tg, tb, 0, stream>>>(Wo, Wto);
  pack_wbm_kernel<<<160, 256, 0, stream>>>(Wb, Wm, Wtf);

  dim3 gqkv(24, 32);
  gemm_pipe_kernel<0><<<gqkv, 256, 0, stream>>>(Xb, Wqkvt, Qb, Kb, Vb, nullptr, nullptr, nullptr);

  rw2_kernel<<<4096, 256, 0, stream>>>(x, Wtf, bb, bm, base_logit, Rf, Wsf);
  decay2_kernel<<<256, 256, 0, stream>>>(Rf, Wsf, mask, WAf, IAf, DUf, ACf);

  chunkA_kernel<<<256, 512, 0, stream>>>(Qb, Kb, Vb, WAf, IAf, DUf, Olocal, UTb);
  chainB_kernel<<<4096, 256, 0, stream>>>(UTb, ACf, S0T);
  chunkC_kernel<<<256, 512, 0, stream>>>(Qb, S0T, WAf, Olocal, Ob);

  dim3 gwo(8, 32);
  gemm_pipe_kernel<1><<<gwo, 256, 0, stream>>>(Ob, Wto, nullptr, nullptr, nullptr, Yf, bo, x);

  ln_kernel<<<4096, 256, 0, stream>>>(Yf, ln_g, ln_b, (float*)d_out);
}

// Round 7
// 176.376 us; speedup vs baseline: 8.5196x; 1.1215x over previous
//
#include <hip/hip_runtime.h>
#include <hip/hip_bf16.h>
#include <math.h>

#define TSEQ 2048
#define NHID 1024

typedef float f32x4 __attribute__((ext_vector_type(4)));
typedef __bf16 bf16x8 __attribute__((ext_vector_type(8)));

static __device__ __forceinline__ unsigned short f2bf(float f) {
  unsigned u = __float_as_uint(f);
  u += 0x7fffu + ((u >> 16) & 1u);
  return (unsigned short)(u >> 16);
}
static __device__ __forceinline__ float bf2f(unsigned short h) {
  return __uint_as_float(((unsigned)h) << 16);
}

#define GLDS16(g, l) __builtin_amdgcn_global_load_lds( \
    (const __attribute__((address_space(1))) unsigned int*)(g), \
    (__attribute__((address_space(3))) unsigned int*)(l), 16, 0, 0)

// ------------- transpose 4x 1024x1024 f32 (K,N) -> bf16 (N,K) -------------
__global__ __launch_bounds__(256) void transpose_all_kernel(
    const float* __restrict__ Wq, const float* __restrict__ Wk,
    const float* __restrict__ Wv, const float* __restrict__ Wo,
    unsigned short* __restrict__ Wqkvt, unsigned short* __restrict__ Wto) {
  __shared__ float tile[32][33];
  const float* W;
  unsigned short* Wt;
  int m = blockIdx.z;
  if (m == 0)      { W = Wq; Wt = Wqkvt; }
  else if (m == 1) { W = Wk; Wt = Wqkvt + 1024 * 1024; }
  else if (m == 2) { W = Wv; Wt = Wqkvt + 2 * 1024 * 1024; }
  else             { W = Wo; Wt = Wto; }
  int bx = blockIdx.x * 32;
  int by = blockIdx.y * 32;
  int tx = threadIdx.x, ty = threadIdx.y;
#pragma unroll
  for (int i = 0; i < 32; i += 8)
    tile[ty + i][tx] = W[(size_t)(by + ty + i) * NHID + bx + tx];
  __syncthreads();
#pragma unroll
  for (int i = 0; i < 32; i += 8)
    Wt[(size_t)(bx + ty + i) * NHID + by + tx] = f2bf(tile[tx][ty + i]);
}

// ------------- bf16 MFMA GEMM, 3-buffer LDS + counted vmcnt(8) -------------
// A: bf16 [4096][1024]; Bt: bf16 [N][1024] (N-major, K contiguous)
// MODE 0: fused QKV (Bt 3072 rows); cols<2048 get elu+1; bf16 out Oq/Ok/Ov
// MODE 1: Wo: + bias[col] + res -> f32 Cf
template <int MODE>
__global__ __launch_bounds__(256) void gemm_pipe_kernel(
    const unsigned short* __restrict__ A, const unsigned short* __restrict__ Bt,
    unsigned short* __restrict__ Oq, unsigned short* __restrict__ Ok,
    unsigned short* __restrict__ Ov, float* __restrict__ Cf,
    const float* __restrict__ bias, const float* __restrict__ res) {
  __shared__ __align__(16) unsigned short As[3 * 4096];
  __shared__ __align__(16) unsigned short Bs[3 * 4096];
  const int tid = threadIdx.x;
  const int lane = tid & 63;
  const int wave = tid >> 6;
  const int wr = wave >> 1, wc = wave & 1;
  const int rowBase = blockIdx.y * 128;
  const int colBase = blockIdx.x * 128;

  // staging chunks: c = wave*128 + {lane, lane+64}; row=c>>2; LDS byte off = c*16
  // global k-chunk pre-swizzled: kc = (c&3) ^ ((row>>1)&3)
  const int c0 = wave * 128 + lane;
  const int c1 = c0 + 64;
  const int r0 = c0 >> 2, kc0 = (c0 & 3) ^ ((r0 >> 1) & 3);
  const int r1 = c1 >> 2, kc1 = (c1 & 3) ^ ((r1 >> 1) & 3);
  const unsigned short* gA0 = A + (size_t)(rowBase + r0) * 1024 + kc0 * 8;
  const unsigned short* gA1 = A + (size_t)(rowBase + r1) * 1024 + kc1 * 8;
  const unsigned short* gB0 = Bt + (size_t)(colBase + r0) * 1024 + kc0 * 8;
  const unsigned short* gB1 = Bt + (size_t)(colBase + r1) * 1024 + kc1 * 8;
  const int wofs = wave * 1024;   // shorts; +512 for second chunk-group

  const int kq = lane >> 4;
  const int r16 = lane & 15;

  f32x4 acc[4][4] = {};

#define STAGE(buf, k0)                                       \
  do {                                                       \
    GLDS16(gA0 + (k0), &As[(buf) * 4096 + wofs]);            \
    GLDS16(gA1 + (k0), &As[(buf) * 4096 + wofs + 512]);      \
    GLDS16(gB0 + (k0), &Bs[(buf) * 4096 + wofs]);            \
    GLDS16(gB1 + (k0), &Bs[(buf) * 4096 + wofs + 512]);      \
  } while (0)

  STAGE(0, 0);
  STAGE(1, 32);
  int cur = 0, stg = 2;
  for (int t = 0; t < 32; ++t) {
    if (t < 30) {
      STAGE(stg, (t + 2) * 32);
      asm volatile("s_waitcnt vmcnt(8)" ::: "memory");
    } else if (t == 30) {
      asm volatile("s_waitcnt vmcnt(4)" ::: "memory");
    } else {
      asm volatile("s_waitcnt vmcnt(0)" ::: "memory");
    }
    __builtin_amdgcn_s_barrier();
    asm volatile("" ::: "memory");
    const unsigned short* Ac = &As[cur * 4096];
    const unsigned short* Bc = &Bs[cur * 4096];
    bf16x8 af[4], bfr[4];
#pragma unroll
    for (int m = 0; m < 4; ++m) {
      int row = wr * 64 + m * 16 + r16;
      af[m] = *(const bf16x8*)(Ac + row * 32 + (kq ^ ((row >> 1) & 3)) * 8);
      int colr = wc * 64 + m * 16 + r16;
      bfr[m] = *(const bf16x8*)(Bc + colr * 32 + (kq ^ ((colr >> 1) & 3)) * 8);
    }
    __builtin_amdgcn_s_setprio(1);
#pragma unroll
    for (int m = 0; m < 4; ++m)
#pragma unroll
      for (int n = 0; n < 4; ++n)
        acc[m][n] = __builtin_amdgcn_mfma_f32_16x16x32_bf16(af[m], bfr[n], acc[m][n], 0, 0, 0);
    __builtin_amdgcn_s_setprio(0);
    asm volatile("" ::: "memory");
    __builtin_amdgcn_s_barrier();
    asm volatile("" ::: "memory");
    cur = (cur == 2) ? 0 : cur + 1;
    stg = (stg == 2) ? 0 : stg + 1;
  }
#undef STAGE

  const int r4 = (lane >> 4) * 4;
  if (MODE == 1) {
#pragma unroll
    for (int m = 0; m < 4; ++m)
#pragma unroll
      for (int n = 0; n < 4; ++n) {
        int col = colBase + wc * 64 + n * 16 + r16;
#pragma unroll
        for (int j = 0; j < 4; ++j) {
          int row = rowBase + wr * 64 + m * 16 + r4 + j;
          Cf[(size_t)row * 1024 + col] = acc[m][n][j] + bias[col] + res[(size_t)row * 1024 + col];
        }
      }
  } else {
    unsigned short* outp;
    int cb;
    bool elu;
    if (colBase < 1024)      { outp = Oq; cb = colBase;        elu = true;  }
    else if (colBase < 2048) { outp = Ok; cb = colBase - 1024; elu = true;  }
    else                     { outp = Ov; cb = colBase - 2048; elu = false; }
#pragma unroll
    for (int m = 0; m < 4; ++m)
#pragma unroll
      for (int n = 0; n < 4; ++n) {
        int col = cb + wc * 64 + n * 16 + r16;
#pragma unroll
        for (int j = 0; j < 4; ++j) {
          int row = rowBase + wr * 64 + m * 16 + r4 + j;
          float v = acc[m][n][j];
          if (elu) v = (v > 0.f) ? (v + 1.f) : expf(v);
          outp[(size_t)row * 1024 + col] = f2bf(v);
        }
      }
  }
}

// ------------- pack Wb (1024x8) | Wm (1024x32) -> Wt f32 [40][1024] -------------
__global__ __launch_bounds__(256) void pack_wbm_kernel(const float* __restrict__ Wb,
    const float* __restrict__ Wm, float* __restrict__ Wt) {
  int id = blockIdx.x * 256 + threadIdx.x;
  if (id >= 40960) return;
  int o = id >> 10, i = id & 1023;
  Wt[id] = (o < 8) ? Wb[i * 8 + o] : Wm[i * 32 + (o - 8)];
}

// ------------- per-(b,t): decay/softmax weights + fused x->bf16 cast -------------
__global__ __launch_bounds__(256) void rw2_kernel(const float* __restrict__ x,
    const float* __restrict__ Wt, const float* __restrict__ bb,
    const float* __restrict__ bm, const float* __restrict__ base_logit,
    float* __restrict__ R, float* __restrict__ Wsm,
    unsigned short* __restrict__ Xb) {
  int row = blockIdx.x;
  __shared__ float xs[1024];
  __shared__ float outs[40];
  int tid = threadIdx.x;
  float4 xv = *(const float4*)(x + (size_t)row * 1024 + tid * 4);
  *(float4*)(xs + tid * 4) = xv;
  ushort4 xo;
  xo.x = f2bf(xv.x); xo.y = f2bf(xv.y); xo.z = f2bf(xv.z); xo.w = f2bf(xv.w);
  *(ushort4*)(Xb + (size_t)row * 1024 + tid * 4) = xo;
  __syncthreads();
  int wave = tid >> 6, lane = tid & 63;
  for (int o = wave; o < 40; o += 4) {
    const float* wr = Wt + o * 1024;
    float sum = 0.f;
#pragma unroll
    for (int it = 0; it < 16; ++it) {
      int i = it * 64 + lane;
      sum += xs[i] * wr[i];
    }
#pragma unroll
    for (int off = 32; off > 0; off >>= 1) sum += __shfl_down(sum, off);
    if (lane == 0) outs[o] = sum;
  }
  __syncthreads();
  if (tid < 32) {
    int h = tid >> 2;
    float beta = 1.f / (1.f + expf(-(outs[h] + bb[h])));
    float br = 1.f / (1.f + expf(-base_logit[tid]));
    float r = fminf(fmaxf(beta * br, 0.f), 0.999995f);
    float mval = outs[8 + tid] + bm[tid];
    float mx = fmaxf(mval, __shfl_xor(mval, 1));
    mx = fmaxf(mx, __shfl_xor(mx, 2));
    float ex = expf(mval - mx);
    float ssum = ex + __shfl_xor(ex, 1);
    ssum += __shfl_xor(ssum, 2);
    R[(size_t)row * 32 + tid] = r;
    Wsm[(size_t)row * 32 + tid] = ex / ssum;
  }
}

// ------------- decay precompute via wave product-scan -------------
__global__ __launch_bounds__(256) void decay2_kernel(const float* __restrict__ R,
    const float* __restrict__ Wsm, const float* __restrict__ mask,
    float* __restrict__ WA, float* __restrict__ IA, float* __restrict__ DU,
    float* __restrict__ AC) {
  int wave = threadIdx.x >> 6, lane = threadIdx.x & 63;
  int id = blockIdx.x * 4 + wave;
  int c = id & 15, k = (id >> 4) & 3, bh = id >> 6;
  int b = bh >> 3, h = bh & 7;
  int row0 = b * TSEQ + c * 128 + 2 * lane;
  float m0 = mask[row0], m1 = mask[row0 + 1];
  size_t i0 = (size_t)row0 * 32 + h * 4 + k;
  float rr0 = (m0 > 0.f) ? R[i0] : 1.f;
  float rr1 = (m1 > 0.f) ? R[i0 + 32] : 1.f;
  float incl = rr0 * rr1;
#pragma unroll
  for (int off = 1; off < 64; off <<= 1) {
    float o = __shfl_up(incl, off);
    if (lane >= off) incl *= o;
  }
  float excl = __shfl_up(incl, 1);
  if (lane == 0) excl = 1.f;
  float a0 = fmaxf(excl * rr0, 1e-25f);
  float a1 = fmaxf(a0 * rr1, 1e-25f);
  float aC = __shfl(a1, 63);
  if (lane == 63) AC[(bh * 16 + c) * 4 + k] = a1;
  bool v0 = m0 > 0.f, v1 = m1 > 0.f;
  float w0 = Wsm[i0], w1 = Wsm[i0 + 32];
  int dub = ((bh * 16 + c) * 4 + k) * 128 + 2 * lane;
  WA[i0] = v0 ? w0 * a0 : 0.f;
  WA[i0 + 32] = v1 ? w1 * a1 : 0.f;
  IA[i0] = v0 ? 1.f / a0 : 0.f;
  IA[i0 + 32] = v1 ? 1.f / a1 : 0.f;
  DU[dub] = v0 ? aC / a0 : 0.f;
  DU[dub + 1] = v1 ? aC / a1 : 0.f;
}

// ------------- kernel A: per (bh,chunk): local attention-form + U^T -------------
__global__ __launch_bounds__(512) void chunkA_kernel(
    const unsigned short* __restrict__ Qb, const unsigned short* __restrict__ Kb,
    const unsigned short* __restrict__ Vb,
    const float* __restrict__ WA, const float* __restrict__ IA,
    const float* __restrict__ DU,
    float* __restrict__ Olocal, unsigned short* __restrict__ UT) {
  __shared__ __align__(16) char KTl[32768];
  __shared__ __align__(16) char VTl[32768];
  __shared__ __align__(16) char Pl[32768];
  __shared__ __align__(16) float WAl[128][4];
  __shared__ __align__(16) float IAl[128][4];
  __shared__ float DUl[4][128];

  int wg = blockIdx.x;
  int bh = wg >> 4, c = wg & 15;
  int b = bh >> 3, h = bh & 7;
  int t0 = c * 128;
  int tid = threadIdx.x;
  int lane = tid & 63, wave = tid >> 6;
  int wbase = wave * 16;
  int l15 = lane & 15, lq = lane >> 4;

  const size_t qkvbase = ((size_t)b * TSEQ + t0) * 1024 + h * 128;

  for (int it = 0; it < 4; ++it) {
    int ci = tid + it * 512;
    int t = ci >> 4, s = ci & 15;
    bf16x8 kv = *(const bf16x8*)(Kb + qkvbase + (size_t)t * 1024 + s * 8);
    bf16x8 vv = *(const bf16x8*)(Vb + qkvbase + (size_t)t * 1024 + s * 8);
#pragma unroll
    for (int e = 0; e < 8; ++e) {
      int d = s * 8 + e;
      int off = d * 256 + (((t >> 3) ^ (d & 7)) << 4) + (t & 7) * 2;
      *(unsigned short*)(KTl + off) = f2bf((float)kv[e]);
      *(unsigned short*)(VTl + off) = f2bf((float)vv[e]);
    }
  }
  {
    int t = tid >> 2, k = tid & 3;
    size_t idx = ((size_t)b * TSEQ + t0 + t) * 32 + h * 4 + k;
    WAl[t][k] = WA[idx];
    IAl[t][k] = IA[idx];
    int k2 = tid >> 7, j = tid & 127;
    DUl[k2][j] = DU[((bh * 16 + c) * 4 + k2) * 128 + j];
  }
  __syncthreads();

  bf16x8 qf[4];
#pragma unroll
  for (int ds = 0; ds < 4; ++ds)
    qf[ds] = *(const bf16x8*)(Qb + qkvbase + (size_t)(wbase + l15) * 1024 + ds * 32 + lq * 8);
  f32x4 accP[8];
#pragma unroll
  for (int jf = 0; jf < 8; ++jf) {
    f32x4 a = {};
#pragma unroll
    for (int ds = 0; ds < 4; ++ds) {
      bf16x8 kfrag = *(const bf16x8*)(Kb + qkvbase + (size_t)(jf * 16 + l15) * 1024 + ds * 32 + lq * 8);
      a = __builtin_amdgcn_mfma_f32_16x16x32_bf16(qf[ds], kfrag, a, 0, 0, 0);
    }
    accP[jf] = a;
  }

  float4 wa4[4];
#pragma unroll
  for (int jj = 0; jj < 4; ++jj)
    wa4[jj] = *(const float4*)&WAl[wbase + lq * 4 + jj][0];
#pragma unroll
  for (int jf = 0; jf < 8; ++jf) {
    float4 ia4 = *(const float4*)&IAl[jf * 16 + l15][0];
#pragma unroll
    for (int jj = 0; jj < 4; ++jj) {
      int tl = wbase + lq * 4 + jj;
      int jl = jf * 16 + l15;
      float m = 0.f;
      if (jl <= tl)
        m = wa4[jj].x * ia4.x + wa4[jj].y * ia4.y + wa4[jj].z * ia4.z + wa4[jj].w * ia4.w;
      float pv = accP[jf][jj] * m;
      int off = tl * 256 + (((jl >> 3) ^ (tl & 7)) << 4) + (jl & 7) * 2;
      *(unsigned short*)(Pl + off) = f2bf(pv);
    }
  }

  bf16x8 pf[4];
#pragma unroll
  for (int js = 0; js < 4; ++js) {
    int tl = wbase + l15;
    int slot = js * 4 + lq;
    pf[js] = *(const bf16x8*)(Pl + tl * 256 + ((slot ^ (tl & 7)) << 4));
  }
#pragma unroll
  for (int dvf = 0; dvf < 8; ++dvf) {
    f32x4 a = {};
    int dv = dvf * 16 + l15;
#pragma unroll
    for (int js = 0; js < 4; ++js) {
      int slot = js * 4 + lq;
      bf16x8 vfrag = *(const bf16x8*)(VTl + dv * 256 + ((slot ^ (dv & 7)) << 4));
      a = __builtin_amdgcn_mfma_f32_16x16x32_bf16(pf[js], vfrag, a, 0, 0, 0);
    }
#pragma unroll
    for (int jj = 0; jj < 4; ++jj) {
      int tl = wbase + lq * 4 + jj;
      Olocal[((size_t)b * TSEQ + t0 + tl) * 1024 + h * 128 + dv] = a[jj];
    }
  }

  if (c < 15) {
#pragma unroll 1
    for (int k = 0; k < 4; ++k) {
      f32x4 accU[8] = {};
#pragma unroll 1
      for (int js = 0; js < 4; ++js) {
        int dvr = wbase + l15;
        int slot = js * 4 + lq;
        bf16x8 af = *(const bf16x8*)(VTl + dvr * 256 + ((slot ^ (dvr & 7)) << 4));
        int j0 = js * 32 + lq * 8;
        bf16x8 afs;
#pragma unroll
        for (int e = 0; e < 8; ++e)
          afs[e] = (__bf16)((float)af[e] * DUl[k][j0 + e]);
#pragma unroll
        for (int dkf = 0; dkf < 8; ++dkf) {
          int dk = dkf * 16 + l15;
          bf16x8 kf = *(const bf16x8*)(KTl + dk * 256 + ((slot ^ (dk & 7)) << 4));
          accU[dkf] = __builtin_amdgcn_mfma_f32_16x16x32_bf16(afs, kf, accU[dkf], 0, 0, 0);
        }
      }
      size_t ub = (((size_t)bh * 16 + c) * 4 + k) * 16384;
#pragma unroll
      for (int dkf = 0; dkf < 8; ++dkf) {
        int dk = dkf * 16 + l15;
#pragma unroll
        for (int jj = 0; jj < 4; ++jj) {
          int dvr = wbase + lq * 4 + jj;
          UT[ub + (size_t)dvr * 128 + dk] = f2bf(accU[dkf][jj]);
        }
      }
    }
  }
}

// ------------- kernel B: chain states S <- aC*S + U -------------
__global__ __launch_bounds__(256) void chainB_kernel(const unsigned short* __restrict__ UT,
    const float* __restrict__ AC, unsigned short* __restrict__ S0T) {
  int id = blockIdx.x * 256 + threadIdx.x;
  int dk = id & 127;
  int dv = (id >> 7) & 127;
  int k = (id >> 14) & 3;
  int bh = id >> 16;
  size_t elem = (size_t)dv * 128 + dk;
  float S = 0.f;
#pragma unroll 1
  for (int c = 0; c < 15; ++c) {
    size_t ub = (((size_t)bh * 16 + c) * 4 + k) * 16384;
    float u = bf2f(UT[ub + elem]);
    float aC = AC[(bh * 16 + c) * 4 + k];
    S = aC * S + u;
    size_t sb = (((size_t)bh * 16 + (c + 1)) * 4 + k) * 16384;
    S0T[sb + elem] = f2bf(S);
  }
}

// ------------- kernel C: cross-chunk O += sum_k diag(w*a) Q @ S0^k -------------
__global__ __launch_bounds__(512) void chunkC_kernel(const unsigned short* __restrict__ Qb,
    const unsigned short* __restrict__ S0T, const float* __restrict__ WA,
    const float* __restrict__ Olocal, unsigned short* __restrict__ Ob) {
  __shared__ __align__(16) char Sl[32768];
  int wg = blockIdx.x;
  int bh = wg >> 4, c = wg & 15;
  int b = bh >> 3, h = bh & 7;
  int t0 = c * 128;
  int tid = threadIdx.x, lane = tid & 63, wave = tid >> 6;
  int l15 = lane & 15, lq = lane >> 4, wbase = wave * 16;
  size_t qbase = ((size_t)b * TSEQ + t0) * 1024 + h * 128;

  f32x4 accO[8] = {};
  if (c > 0) {
    int tl = wbase + l15;
#pragma unroll 1
    for (int k = 0; k < 4; ++k) {
      __syncthreads();
      size_t sb = (((size_t)bh * 16 + c) * 4 + k) * 16384;
      for (int it = 0; it < 4; ++it) {
        int ci = tid + it * 512;
        int dv = ci >> 4, s = ci & 15;
        bf16x8 vv = *(const bf16x8*)(S0T + sb + (size_t)dv * 128 + s * 8);
        *(bf16x8*)(Sl + dv * 256 + ((s ^ (dv & 7)) << 4)) = vv;
      }
      __syncthreads();
      float sc = WA[((size_t)b * TSEQ + t0 + tl) * 32 + h * 4 + k];
#pragma unroll 1
      for (int ds = 0; ds < 4; ++ds) {
        bf16x8 qf = *(const bf16x8*)(Qb + qbase + (size_t)tl * 1024 + ds * 32 + lq * 8);
        bf16x8 qs;
#pragma unroll
        for (int e = 0; e < 8; ++e) qs[e] = (__bf16)((float)qf[e] * sc);
#pragma unroll
        for (int dvf = 0; dvf < 8; ++dvf) {
          int dv = dvf * 16 + l15;
          int slot = ds * 4 + lq;
          bf16x8 sf = *(const bf16x8*)(Sl + dv * 256 + ((slot ^ (dv & 7)) << 4));
          accO[dvf] = __builtin_amdgcn_mfma_f32_16x16x32_bf16(qs, sf, accO[dvf], 0, 0, 0);
        }
      }
    }
  }
#pragma unroll
  for (int dvf = 0; dvf < 8; ++dvf) {
    int dv = dvf * 16 + l15;
#pragma unroll
    for (int jj = 0; jj < 4; ++jj) {
      int tl = wbase + lq * 4 + jj;
      size_t off = ((size_t)b * TSEQ + t0 + tl) * 1024 + h * 128 + dv;
      Ob[off] = f2bf(accO[dvf][jj] + Olocal[off]);
    }
  }
}

// ------------- LayerNorm (two-pass, per row) -> f32 out -------------
__global__ __launch_bounds__(256) void ln_kernel(const float* __restrict__ Y,
    const float* __restrict__ g, const float* __restrict__ bta,
    float* __restrict__ out) {
  int row = blockIdx.x;
  int tid = threadIdx.x;
  int lane = tid & 63, wave = tid >> 6;
  __shared__ float red[8];
  const float* yr = Y + (size_t)row * 1024;
  float4 v = *(const float4*)(yr + tid * 4);
  float sum = v.x + v.y + v.z + v.w;
#pragma unroll
  for (int off = 32; off > 0; off >>= 1) sum += __shfl_down(sum, off);
  if (lane == 0) red[wave] = sum;
  __syncthreads();
  float mu = (red[0] + red[1] + red[2] + red[3]) * (1.f / 1024.f);
  float4 d;
  d.x = v.x - mu; d.y = v.y - mu; d.z = v.z - mu; d.w = v.w - mu;
  float sq = d.x * d.x + d.y * d.y + d.z * d.z + d.w * d.w;
#pragma unroll
  for (int off = 32; off > 0; off >>= 1) sq += __shfl_down(sq, off);
  __syncthreads();
  if (lane == 0) red[4 + wave] = sq;
  __syncthreads();
  float var = (red[4] + red[5] + red[6] + red[7]) * (1.f / 1024.f);
  float inv = rsqrtf(var + 1e-5f);
  float4 gg = *(const float4*)(g + tid * 4);
  float4 bb4 = *(const float4*)(bta + tid * 4);
  float4 o;
  o.x = d.x * inv * gg.x + bb4.x;
  o.y = d.y * inv * gg.y + bb4.y;
  o.z = d.z * inv * gg.z + bb4.z;
  o.w = d.w * inv * gg.w + bb4.w;
  *(float4*)(out + (size_t)row * 1024 + tid * 4) = o;
}

extern "C" void kernel_launch(void* const* d_in, const int* in_sizes, int n_in,
                              void* d_out, int out_size, void* d_ws, size_t ws_size,
                              hipStream_t stream) {
  const float* x    = (const float*)d_in[0];
  const float* mask = (const float*)d_in[1];
  const float* Wq   = (const float*)d_in[2];
  const float* Wk   = (const float*)d_in[3];
  const float* Wv   = (const float*)d_in[4];
  const float* Wb   = (const float*)d_in[5];
  const float* bb   = (const float*)d_in[6];
  const float* Wm   = (const float*)d_in[7];
  const float* bm   = (const float*)d_in[8];
  const float* Wo   = (const float*)d_in[9];
  const float* bo   = (const float*)d_in[10];
  const float* base_logit = (const float*)d_in[11];
  const float* ln_g = (const float*)d_in[12];
  const float* ln_b = (const float*)d_in[13];

  char* ws = (char*)d_ws;
  const size_t MB = 1024u * 1024u;
  unsigned short* Xb    = (unsigned short*)(ws + 0);
  unsigned short* Wqkvt = (unsigned short*)(ws + 8 * MB);   // [3072][1024] bf16
  unsigned short* Wto   = (unsigned short*)(ws + 14 * MB);
  float* Rf  = (float*)(ws + 16 * MB);
  float* Wsf = (float*)(ws + 16 * MB + 512 * 1024);
  float* WAf = (float*)(ws + 17 * MB);
  float* IAf = (float*)(ws + 17 * MB + 512 * 1024);
  float* DUf = (float*)(ws + 18 * MB);
  float* ACf = (float*)(ws + 18 * MB + 512 * 1024);
  float* Wtf = (float*)(ws + 18 * MB + 768 * 1024);
  unsigned short* Qb = (unsigned short*)(ws + 19 * MB);
  unsigned short* Kb = (unsigned short*)(ws + 27 * MB);
  unsigned short* Vb = (unsigned short*)(ws + 35 * MB);
  float* Olocal = (float*)(ws + 43 * MB);
  unsigned short* Ob = (unsigned short*)(ws + 59 * MB);
  unsigned short* UTb = (unsigned short*)(ws + 67 * MB);
  unsigned short* S0T = (unsigned short*)(ws + 99 * MB);
  float* Yf = Olocal;
  if (ws_size < 131 * MB) return;

  dim3 tb(32, 8), tg(32, 32, 4);
  transpose_all_kernel<<<tg, tb, 0, stream>>>(Wq, Wk, Wv, Wo, Wqkvt, Wto);
  pack_wbm_kernel<<<160, 256, 0, stream>>>(Wb, Wm, Wtf);

  rw2_kernel<<<4096, 256, 0, stream>>>(x, Wtf, bb, bm, base_logit, Rf, Wsf, Xb);
  decay2_kernel<<<256, 256, 0, stream>>>(Rf, Wsf, mask, WAf, IAf, DUf, ACf);

  dim3 gqkv(24, 32);
  gemm_pipe_kernel<0><<<gqkv, 256, 0, stream>>>(Xb, Wqkvt, Qb, Kb, Vb, nullptr, nullptr, nullptr);

  chunkA_kernel<<<256, 512, 0, stream>>>(Qb, Kb, Vb, WAf, IAf, DUf, Olocal, UTb);
  chainB_kernel<<<4096, 256, 0, stream>>>(UTb, ACf, S0T);
  chunkC_kernel<<<256, 512, 0, stream>>>(Qb, S0T, WAf, Olocal, Ob);

  dim3 gwo(8, 32);
  gemm_pipe_kernel<1><<<gwo, 256, 0, stream>>>(Ob, Wto, nullptr, nullptr, nullptr, Yf, bo, x);

  ln_kernel<<<4096, 256, 0, stream>>>(Yf, ln_g, ln_b, (float*)d_out);
}

// Round 8
// 175.256 us; speedup vs baseline: 8.5741x; 1.0064x over previous
//
#include <hip/hip_runtime.h>
#include <hip/hip_bf16.h>
#include <math.h>

#define TSEQ 2048
#define NHID 1024

typedef float f32x4 __attribute__((ext_vector_type(4)));
typedef __bf16 bf16x8 __attribute__((ext_vector_type(8)));

static __device__ __forceinline__ unsigned short f2bf(float f) {
  unsigned u = __float_as_uint(f);
  u += 0x7fffu + ((u >> 16) & 1u);
  return (unsigned short)(u >> 16);
}
static __device__ __forceinline__ float bf2f(unsigned short h) {
  return __uint_as_float(((unsigned)h) << 16);
}

#define GLDS16(g, l) __builtin_amdgcn_global_load_lds( \
    (const __attribute__((address_space(1))) unsigned int*)(g), \
    (__attribute__((address_space(3))) unsigned int*)(l), 16, 0, 0)

// ------------- transpose 4x 1024x1024 f32 (K,N) -> bf16 (N,K) -------------
__global__ __launch_bounds__(256) void transpose_all_kernel(
    const float* __restrict__ Wq, const float* __restrict__ Wk,
    const float* __restrict__ Wv, const float* __restrict__ Wo,
    unsigned short* __restrict__ Wqkvt, unsigned short* __restrict__ Wto) {
  __shared__ float tile[32][33];
  const float* W;
  unsigned short* Wt;
  int m = blockIdx.z;
  if (m == 0)      { W = Wq; Wt = Wqkvt; }
  else if (m == 1) { W = Wk; Wt = Wqkvt + 1024 * 1024; }
  else if (m == 2) { W = Wv; Wt = Wqkvt + 2 * 1024 * 1024; }
  else             { W = Wo; Wt = Wto; }
  int bx = blockIdx.x * 32;
  int by = blockIdx.y * 32;
  int tx = threadIdx.x, ty = threadIdx.y;
#pragma unroll
  for (int i = 0; i < 32; i += 8)
    tile[ty + i][tx] = W[(size_t)(by + ty + i) * NHID + bx + tx];
  __syncthreads();
#pragma unroll
  for (int i = 0; i < 32; i += 8)
    Wt[(size_t)(bx + ty + i) * NHID + by + tx] = f2bf(tile[tx][ty + i]);
}

// ------------- bf16 MFMA GEMM, 3-buffer LDS + counted vmcnt(8) -------------
// MODE 0: fused QKV (Bt 3072 rows, K=1024); cols<2048 elu+1; bf16 out Oq/Ok/Ov
// MODE 1: Wo split-K (K=512 per z); f32 partial out to P (P0/P1 by blockIdx.z)
template <int MODE>
__global__ __launch_bounds__(256) void gemm_pipe_kernel(
    const unsigned short* __restrict__ A, const unsigned short* __restrict__ Bt,
    unsigned short* __restrict__ Oq, unsigned short* __restrict__ Ok,
    unsigned short* __restrict__ Ov, float* __restrict__ P0, float* __restrict__ P1) {
  __shared__ __align__(16) unsigned short As[3 * 4096];
  __shared__ __align__(16) unsigned short Bs[3 * 4096];
  const int tid = threadIdx.x;
  const int lane = tid & 63;
  const int wave = tid >> 6;
  const int wr = wave >> 1, wc = wave & 1;
  const int rowBase = blockIdx.y * 128;
  const int colBase = blockIdx.x * 128;
  const int NT = (MODE == 0) ? 32 : 16;
  const int kOff = (MODE == 0) ? 0 : blockIdx.z * 512;

  const int c0 = wave * 128 + lane;
  const int c1 = c0 + 64;
  const int r0 = c0 >> 2, kc0 = (c0 & 3) ^ ((r0 >> 1) & 3);
  const int r1 = c1 >> 2, kc1 = (c1 & 3) ^ ((r1 >> 1) & 3);
  const unsigned short* gA0 = A + (size_t)(rowBase + r0) * 1024 + kOff + kc0 * 8;
  const unsigned short* gA1 = A + (size_t)(rowBase + r1) * 1024 + kOff + kc1 * 8;
  const unsigned short* gB0 = Bt + (size_t)(colBase + r0) * 1024 + kOff + kc0 * 8;
  const unsigned short* gB1 = Bt + (size_t)(colBase + r1) * 1024 + kOff + kc1 * 8;
  const int wofs = wave * 1024;

  const int kq = lane >> 4;
  const int r16 = lane & 15;

  f32x4 acc[4][4] = {};

#define STAGE(buf, k0)                                       \
  do {                                                       \
    GLDS16(gA0 + (k0), &As[(buf) * 4096 + wofs]);            \
    GLDS16(gA1 + (k0), &As[(buf) * 4096 + wofs + 512]);      \
    GLDS16(gB0 + (k0), &Bs[(buf) * 4096 + wofs]);            \
    GLDS16(gB1 + (k0), &Bs[(buf) * 4096 + wofs + 512]);      \
  } while (0)

  STAGE(0, 0);
  STAGE(1, 32);
  int cur = 0, stg = 2;
  for (int t = 0; t < NT; ++t) {
    if (t < NT - 2) {
      STAGE(stg, (t + 2) * 32);
      asm volatile("s_waitcnt vmcnt(8)" ::: "memory");
    } else if (t == NT - 2) {
      asm volatile("s_waitcnt vmcnt(4)" ::: "memory");
    } else {
      asm volatile("s_waitcnt vmcnt(0)" ::: "memory");
    }
    __builtin_amdgcn_s_barrier();
    asm volatile("" ::: "memory");
    const unsigned short* Ac = &As[cur * 4096];
    const unsigned short* Bc = &Bs[cur * 4096];
    bf16x8 af[4], bfr[4];
#pragma unroll
    for (int m = 0; m < 4; ++m) {
      int row = wr * 64 + m * 16 + r16;
      af[m] = *(const bf16x8*)(Ac + row * 32 + (kq ^ ((row >> 1) & 3)) * 8);
      int colr = wc * 64 + m * 16 + r16;
      bfr[m] = *(const bf16x8*)(Bc + colr * 32 + (kq ^ ((colr >> 1) & 3)) * 8);
    }
#pragma unroll
    for (int m = 0; m < 4; ++m)
#pragma unroll
      for (int n = 0; n < 4; ++n)
        acc[m][n] = __builtin_amdgcn_mfma_f32_16x16x32_bf16(af[m], bfr[n], acc[m][n], 0, 0, 0);
    asm volatile("" ::: "memory");
    __builtin_amdgcn_s_barrier();
    asm volatile("" ::: "memory");
    cur = (cur == 2) ? 0 : cur + 1;
    stg = (stg == 2) ? 0 : stg + 1;
  }
#undef STAGE

  const int r4 = (lane >> 4) * 4;
  if (MODE == 1) {
    float* P = (blockIdx.z == 0) ? P0 : P1;
#pragma unroll
    for (int m = 0; m < 4; ++m)
#pragma unroll
      for (int n = 0; n < 4; ++n) {
        int col = colBase + wc * 64 + n * 16 + r16;
#pragma unroll
        for (int j = 0; j < 4; ++j) {
          int row = rowBase + wr * 64 + m * 16 + r4 + j;
          P[(size_t)row * 1024 + col] = acc[m][n][j];
        }
      }
  } else {
    unsigned short* outp;
    int cb;
    bool elu;
    if (colBase < 1024)      { outp = Oq; cb = colBase;        elu = true;  }
    else if (colBase < 2048) { outp = Ok; cb = colBase - 1024; elu = true;  }
    else                     { outp = Ov; cb = colBase - 2048; elu = false; }
#pragma unroll
    for (int m = 0; m < 4; ++m)
#pragma unroll
      for (int n = 0; n < 4; ++n) {
        int col = cb + wc * 64 + n * 16 + r16;
#pragma unroll
        for (int j = 0; j < 4; ++j) {
          int row = rowBase + wr * 64 + m * 16 + r4 + j;
          float v = acc[m][n][j];
          if (elu) v = (v > 0.f) ? (v + 1.f) : expf(v);
          outp[(size_t)row * 1024 + col] = f2bf(v);
        }
      }
  }
}

// ------------- pack Wb (1024x8) | Wm (1024x32) -> Wt f32 [40][1024] -------------
__global__ __launch_bounds__(256) void pack_wbm_kernel(const float* __restrict__ Wb,
    const float* __restrict__ Wm, float* __restrict__ Wt) {
  int id = blockIdx.x * 256 + threadIdx.x;
  if (id >= 40960) return;
  int o = id >> 10, i = id & 1023;
  Wt[id] = (o < 8) ? Wb[i * 8 + o] : Wm[i * 32 + (o - 8)];
}

// ------------- per-(b,t) decay/softmax weights, 8 rows/block + x cast -------------
__global__ __launch_bounds__(256) void rw8_kernel(const float* __restrict__ x,
    const float* __restrict__ Wt, const float* __restrict__ bb,
    const float* __restrict__ bm, const float* __restrict__ base_logit,
    float* __restrict__ R, float* __restrict__ Wsm,
    unsigned short* __restrict__ Xb) {
  __shared__ float xs[8][1024];
  __shared__ float outs[8][40];
  int row0 = blockIdx.x * 8;
  int tid = threadIdx.x;
#pragma unroll
  for (int r = 0; r < 8; ++r) {
    float4 xv = *(const float4*)(x + (size_t)(row0 + r) * 1024 + tid * 4);
    *(float4*)(&xs[r][tid * 4]) = xv;
    ushort4 xo;
    xo.x = f2bf(xv.x); xo.y = f2bf(xv.y); xo.z = f2bf(xv.z); xo.w = f2bf(xv.w);
    *(ushort4*)(Xb + (size_t)(row0 + r) * 1024 + tid * 4) = xo;
  }
  __syncthreads();
  int wave = tid >> 6, lane = tid & 63;
  for (int o = wave; o < 40; o += 4) {
    const float* wr = Wt + o * 1024;
    float w[16];
#pragma unroll
    for (int it = 0; it < 16; ++it) w[it] = wr[it * 64 + lane];
#pragma unroll
    for (int r = 0; r < 8; ++r) {
      float sum = 0.f;
#pragma unroll
      for (int it = 0; it < 16; ++it) sum += xs[r][it * 64 + lane] * w[it];
#pragma unroll
      for (int off = 32; off > 0; off >>= 1) sum += __shfl_down(sum, off);
      if (lane == 0) outs[r][o] = sum;
    }
  }
  __syncthreads();
  {
    int r = tid >> 5, j = tid & 31;
    int row = row0 + r;
    int h = j >> 2;
    float beta = 1.f / (1.f + expf(-(outs[r][h] + bb[h])));
    float br = 1.f / (1.f + expf(-base_logit[j]));
    float rr = fminf(fmaxf(beta * br, 0.f), 0.999995f);
    float mval = outs[r][8 + j] + bm[j];
    float mx = fmaxf(mval, __shfl_xor(mval, 1));
    mx = fmaxf(mx, __shfl_xor(mx, 2));
    float ex = expf(mval - mx);
    float ssum = ex + __shfl_xor(ex, 1);
    ssum += __shfl_xor(ssum, 2);
    R[(size_t)row * 32 + j] = rr;
    Wsm[(size_t)row * 32 + j] = ex / ssum;
  }
}

// ------------- decay precompute via wave product-scan -------------
__global__ __launch_bounds__(256) void decay2_kernel(const float* __restrict__ R,
    const float* __restrict__ Wsm, const float* __restrict__ mask,
    float* __restrict__ WA, float* __restrict__ IA, float* __restrict__ DU,
    float* __restrict__ AC) {
  int wave = threadIdx.x >> 6, lane = threadIdx.x & 63;
  int id = blockIdx.x * 4 + wave;
  int c = id & 15, k = (id >> 4) & 3, bh = id >> 6;
  int b = bh >> 3, h = bh & 7;
  int row0 = b * TSEQ + c * 128 + 2 * lane;
  float m0 = mask[row0], m1 = mask[row0 + 1];
  size_t i0 = (size_t)row0 * 32 + h * 4 + k;
  float rr0 = (m0 > 0.f) ? R[i0] : 1.f;
  float rr1 = (m1 > 0.f) ? R[i0 + 32] : 1.f;
  float incl = rr0 * rr1;
#pragma unroll
  for (int off = 1; off < 64; off <<= 1) {
    float o = __shfl_up(incl, off);
    if (lane >= off) incl *= o;
  }
  float excl = __shfl_up(incl, 1);
  if (lane == 0) excl = 1.f;
  float a0 = fmaxf(excl * rr0, 1e-25f);
  float a1 = fmaxf(a0 * rr1, 1e-25f);
  float aC = __shfl(a1, 63);
  if (lane == 63) AC[(bh * 16 + c) * 4 + k] = a1;
  bool v0 = m0 > 0.f, v1 = m1 > 0.f;
  float w0 = Wsm[i0], w1 = Wsm[i0 + 32];
  int dub = ((bh * 16 + c) * 4 + k) * 128 + 2 * lane;
  WA[i0] = v0 ? w0 * a0 : 0.f;
  WA[i0 + 32] = v1 ? w1 * a1 : 0.f;
  IA[i0] = v0 ? 1.f / a0 : 0.f;
  IA[i0 + 32] = v1 ? 1.f / a1 : 0.f;
  DU[dub] = v0 ? aC / a0 : 0.f;
  DU[dub + 1] = v1 ? aC / a1 : 0.f;
}

// ------------- kernel A: per (bh,chunk): local attention-form + U^T -------------
__global__ __launch_bounds__(512) void chunkA_kernel(
    const unsigned short* __restrict__ Qb, const unsigned short* __restrict__ Kb,
    const unsigned short* __restrict__ Vb,
    const float* __restrict__ WA, const float* __restrict__ IA,
    const float* __restrict__ DU,
    float* __restrict__ Olocal, unsigned short* __restrict__ UT) {
  __shared__ __align__(16) char KTl[32768];
  __shared__ __align__(16) char VTl[32768];
  __shared__ __align__(16) char Pl[32768];
  __shared__ __align__(16) float WAl[128][4];
  __shared__ __align__(16) float IAl[128][4];
  __shared__ float DUl[4][128];

  int wg = blockIdx.x;
  int bh = wg >> 4, c = wg & 15;
  int b = bh >> 3, h = bh & 7;
  int t0 = c * 128;
  int tid = threadIdx.x;
  int lane = tid & 63, wave = tid >> 6;
  int wbase = wave * 16;
  int l15 = lane & 15, lq = lane >> 4;

  const size_t qkvbase = ((size_t)b * TSEQ + t0) * 1024 + h * 128;

  for (int it = 0; it < 4; ++it) {
    int ci = tid + it * 512;
    int t = ci >> 4, s = ci & 15;
    bf16x8 kv = *(const bf16x8*)(Kb + qkvbase + (size_t)t * 1024 + s * 8);
    bf16x8 vv = *(const bf16x8*)(Vb + qkvbase + (size_t)t * 1024 + s * 8);
#pragma unroll
    for (int e = 0; e < 8; ++e) {
      int d = s * 8 + e;
      int off = d * 256 + (((t >> 3) ^ (d & 7)) << 4) + (t & 7) * 2;
      *(unsigned short*)(KTl + off) = f2bf((float)kv[e]);
      *(unsigned short*)(VTl + off) = f2bf((float)vv[e]);
    }
  }
  {
    int t = tid >> 2, k = tid & 3;
    size_t idx = ((size_t)b * TSEQ + t0 + t) * 32 + h * 4 + k;
    WAl[t][k] = WA[idx];
    IAl[t][k] = IA[idx];
    int k2 = tid >> 7, j = tid & 127;
    DUl[k2][j] = DU[((bh * 16 + c) * 4 + k2) * 128 + j];
  }
  __syncthreads();

  bf16x8 qf[4];
#pragma unroll
  for (int ds = 0; ds < 4; ++ds)
    qf[ds] = *(const bf16x8*)(Qb + qkvbase + (size_t)(wbase + l15) * 1024 + ds * 32 + lq * 8);
  f32x4 accP[8];
#pragma unroll
  for (int jf = 0; jf < 8; ++jf) {
    f32x4 a = {};
#pragma unroll
    for (int ds = 0; ds < 4; ++ds) {
      bf16x8 kfrag = *(const bf16x8*)(Kb + qkvbase + (size_t)(jf * 16 + l15) * 1024 + ds * 32 + lq * 8);
      a = __builtin_amdgcn_mfma_f32_16x16x32_bf16(qf[ds], kfrag, a, 0, 0, 0);
    }
    accP[jf] = a;
  }

  float4 wa4[4];
#pragma unroll
  for (int jj = 0; jj < 4; ++jj)
    wa4[jj] = *(const float4*)&WAl[wbase + lq * 4 + jj][0];
#pragma unroll
  for (int jf = 0; jf < 8; ++jf) {
    float4 ia4 = *(const float4*)&IAl[jf * 16 + l15][0];
#pragma unroll
    for (int jj = 0; jj < 4; ++jj) {
      int tl = wbase + lq * 4 + jj;
      int jl = jf * 16 + l15;
      float m = 0.f;
      if (jl <= tl)
        m = wa4[jj].x * ia4.x + wa4[jj].y * ia4.y + wa4[jj].z * ia4.z + wa4[jj].w * ia4.w;
      float pv = accP[jf][jj] * m;
      int off = tl * 256 + (((jl >> 3) ^ (tl & 7)) << 4) + (jl & 7) * 2;
      *(unsigned short*)(Pl + off) = f2bf(pv);
    }
  }

  bf16x8 pf[4];
#pragma unroll
  for (int js = 0; js < 4; ++js) {
    int tl = wbase + l15;
    int slot = js * 4 + lq;
    pf[js] = *(const bf16x8*)(Pl + tl * 256 + ((slot ^ (tl & 7)) << 4));
  }
#pragma unroll
  for (int dvf = 0; dvf < 8; ++dvf) {
    f32x4 a = {};
    int dv = dvf * 16 + l15;
#pragma unroll
    for (int js = 0; js < 4; ++js) {
      int slot = js * 4 + lq;
      bf16x8 vfrag = *(const bf16x8*)(VTl + dv * 256 + ((slot ^ (dv & 7)) << 4));
      a = __builtin_amdgcn_mfma_f32_16x16x32_bf16(pf[js], vfrag, a, 0, 0, 0);
    }
#pragma unroll
    for (int jj = 0; jj < 4; ++jj) {
      int tl = wbase + lq * 4 + jj;
      Olocal[((size_t)b * TSEQ + t0 + tl) * 1024 + h * 128 + dv] = a[jj];
    }
  }

  if (c < 15) {
#pragma unroll 1
    for (int k = 0; k < 4; ++k) {
      f32x4 accU[8] = {};
#pragma unroll 1
      for (int js = 0; js < 4; ++js) {
        int dvr = wbase + l15;
        int slot = js * 4 + lq;
        bf16x8 af = *(const bf16x8*)(VTl + dvr * 256 + ((slot ^ (dvr & 7)) << 4));
        int j0 = js * 32 + lq * 8;
        bf16x8 afs;
#pragma unroll
        for (int e = 0; e < 8; ++e)
          afs[e] = (__bf16)((float)af[e] * DUl[k][j0 + e]);
#pragma unroll
        for (int dkf = 0; dkf < 8; ++dkf) {
          int dk = dkf * 16 + l15;
          bf16x8 kf = *(const bf16x8*)(KTl + dk * 256 + ((slot ^ (dk & 7)) << 4));
          accU[dkf] = __builtin_amdgcn_mfma_f32_16x16x32_bf16(afs, kf, accU[dkf], 0, 0, 0);
        }
      }
      size_t ub = (((size_t)bh * 16 + c) * 4 + k) * 16384;
#pragma unroll
      for (int dkf = 0; dkf < 8; ++dkf) {
        int dk = dkf * 16 + l15;
#pragma unroll
        for (int jj = 0; jj < 4; ++jj) {
          int dvr = wbase + lq * 4 + jj;
          UT[ub + (size_t)dvr * 128 + dk] = f2bf(accU[dkf][jj]);
        }
      }
    }
  }
}

// ------------- kernel B: chain states S <- aC*S + U -------------
__global__ __launch_bounds__(256) void chainB_kernel(const unsigned short* __restrict__ UT,
    const float* __restrict__ AC, unsigned short* __restrict__ S0T) {
  int id = blockIdx.x * 256 + threadIdx.x;
  int dk = id & 127;
  int dv = (id >> 7) & 127;
  int k = (id >> 14) & 3;
  int bh = id >> 16;
  size_t elem = (size_t)dv * 128 + dk;
  float S = 0.f;
#pragma unroll 1
  for (int c = 0; c < 15; ++c) {
    size_t ub = (((size_t)bh * 16 + c) * 4 + k) * 16384;
    float u = bf2f(UT[ub + elem]);
    float aC = AC[(bh * 16 + c) * 4 + k];
    S = aC * S + u;
    size_t sb = (((size_t)bh * 16 + (c + 1)) * 4 + k) * 16384;
    S0T[sb + elem] = f2bf(S);
  }
}

// ------------- kernel C: cross-chunk O += sum_k diag(w*a) Q @ S0^k -------------
__global__ __launch_bounds__(512) void chunkC_kernel(const unsigned short* __restrict__ Qb,
    const unsigned short* __restrict__ S0T, const float* __restrict__ WA,
    const float* __restrict__ Olocal, unsigned short* __restrict__ Ob) {
  __shared__ __align__(16) char Sl[32768];
  int wg = blockIdx.x;
  int bh = wg >> 4, c = wg & 15;
  int b = bh >> 3, h = bh & 7;
  int t0 = c * 128;
  int tid = threadIdx.x, lane = tid & 63, wave = tid >> 6;
  int l15 = lane & 15, lq = lane >> 4, wbase = wave * 16;
  size_t qbase = ((size_t)b * TSEQ + t0) * 1024 + h * 128;

  f32x4 accO[8] = {};
  if (c > 0) {
    int tl = wbase + l15;
#pragma unroll 1
    for (int k = 0; k < 4; ++k) {
      __syncthreads();
      size_t sb = (((size_t)bh * 16 + c) * 4 + k) * 16384;
      for (int it = 0; it < 4; ++it) {
        int ci = tid + it * 512;
        int dv = ci >> 4, s = ci & 15;
        bf16x8 vv = *(const bf16x8*)(S0T + sb + (size_t)dv * 128 + s * 8);
        *(bf16x8*)(Sl + dv * 256 + ((s ^ (dv & 7)) << 4)) = vv;
      }
      __syncthreads();
      float sc = WA[((size_t)b * TSEQ + t0 + tl) * 32 + h * 4 + k];
#pragma unroll 1
      for (int ds = 0; ds < 4; ++ds) {
        bf16x8 qf = *(const bf16x8*)(Qb + qbase + (size_t)tl * 1024 + ds * 32 + lq * 8);
        bf16x8 qs;
#pragma unroll
        for (int e = 0; e < 8; ++e) qs[e] = (__bf16)((float)qf[e] * sc);
#pragma unroll
        for (int dvf = 0; dvf < 8; ++dvf) {
          int dv = dvf * 16 + l15;
          int slot = ds * 4 + lq;
          bf16x8 sf = *(const bf16x8*)(Sl + dv * 256 + ((slot ^ (dv & 7)) << 4));
          accO[dvf] = __builtin_amdgcn_mfma_f32_16x16x32_bf16(qs, sf, accO[dvf], 0, 0, 0);
        }
      }
    }
  }
#pragma unroll
  for (int dvf = 0; dvf < 8; ++dvf) {
    int dv = dvf * 16 + l15;
#pragma unroll
    for (int jj = 0; jj < 4; ++jj) {
      int tl = wbase + lq * 4 + jj;
      size_t off = ((size_t)b * TSEQ + t0 + tl) * 1024 + h * 128 + dv;
      Ob[off] = f2bf(accO[dvf][jj] + Olocal[off]);
    }
  }
}

// ------- LayerNorm: y = P0+P1+bo+x, then LN -> f32 out -------
__global__ __launch_bounds__(256) void ln_kernel(const float* __restrict__ P0,
    const float* __restrict__ P1, const float* __restrict__ bo,
    const float* __restrict__ xres,
    const float* __restrict__ g, const float* __restrict__ bta,
    float* __restrict__ out) {
  int row = blockIdx.x;
  int tid = threadIdx.x;
  int lane = tid & 63, wave = tid >> 6;
  __shared__ float red[8];
  size_t base = (size_t)row * 1024 + tid * 4;
  float4 a = *(const float4*)(P0 + base);
  float4 b2 = *(const float4*)(P1 + base);
  float4 xv = *(const float4*)(xres + base);
  float4 bv = *(const float4*)(bo + tid * 4);
  float4 v;
  v.x = a.x + b2.x + bv.x + xv.x;
  v.y = a.y + b2.y + bv.y + xv.y;
  v.z = a.z + b2.z + bv.z + xv.z;
  v.w = a.w + b2.w + bv.w + xv.w;
  float sum = v.x + v.y + v.z + v.w;
#pragma unroll
  for (int off = 32; off > 0; off >>= 1) sum += __shfl_down(sum, off);
  if (lane == 0) red[wave] = sum;
  __syncthreads();
  float mu = (red[0] + red[1] + red[2] + red[3]) * (1.f / 1024.f);
  float4 d;
  d.x = v.x - mu; d.y = v.y - mu; d.z = v.z - mu; d.w = v.w - mu;
  float sq = d.x * d.x + d.y * d.y + d.z * d.z + d.w * d.w;
#pragma unroll
  for (int off = 32; off > 0; off >>= 1) sq += __shfl_down(sq, off);
  __syncthreads();
  if (lane == 0) red[4 + wave] = sq;
  __syncthreads();
  float var = (red[4] + red[5] + red[6] + red[7]) * (1.f / 1024.f);
  float inv = rsqrtf(var + 1e-5f);
  float4 gg = *(const float4*)(g + tid * 4);
  float4 bb4 = *(const float4*)(bta + tid * 4);
  float4 o;
  o.x = d.x * inv * gg.x + bb4.x;
  o.y = d.y * inv * gg.y + bb4.y;
  o.z = d.z * inv * gg.z + bb4.z;
  o.w = d.w * inv * gg.w + bb4.w;
  *(float4*)(out + (size_t)row * 1024 + tid * 4) = o;
}

extern "C" void kernel_launch(void* const* d_in, const int* in_sizes, int n_in,
                              void* d_out, int out_size, void* d_ws, size_t ws_size,
                              hipStream_t stream) {
  const float* x    = (const float*)d_in[0];
  const float* mask = (const float*)d_in[1];
  const float* Wq   = (const float*)d_in[2];
  const float* Wk   = (const float*)d_in[3];
  const float* Wv   = (const float*)d_in[4];
  const float* Wb   = (const float*)d_in[5];
  const float* bb   = (const float*)d_in[6];
  const float* Wm   = (const float*)d_in[7];
  const float* bm   = (const float*)d_in[8];
  const float* Wo   = (const float*)d_in[9];
  const float* bo   = (const float*)d_in[10];
  const float* base_logit = (const float*)d_in[11];
  const float* ln_g = (const float*)d_in[12];
  const float* ln_b = (const float*)d_in[13];

  char* ws = (char*)d_ws;
  const size_t MB = 1024u * 1024u;
  unsigned short* Xb    = (unsigned short*)(ws + 0);
  unsigned short* Wqkvt = (unsigned short*)(ws + 8 * MB);   // [3072][1024] bf16
  unsigned short* Wto   = (unsigned short*)(ws + 14 * MB);
  float* Rf  = (float*)(ws + 16 * MB);
  float* Wsf = (float*)(ws + 16 * MB + 512 * 1024);
  float* WAf = (float*)(ws + 17 * MB);
  float* IAf = (float*)(ws + 17 * MB + 512 * 1024);
  float* DUf = (float*)(ws + 18 * MB);
  float* ACf = (float*)(ws + 18 * MB + 512 * 1024);
  float* Wtf = (float*)(ws + 18 * MB + 768 * 1024);
  unsigned short* Qb = (unsigned short*)(ws + 19 * MB);
  unsigned short* Kb = (unsigned short*)(ws + 27 * MB);
  unsigned short* Vb = (unsigned short*)(ws + 35 * MB);
  float* Olocal = (float*)(ws + 43 * MB);                 // 16 MB; later P0
  unsigned short* Ob = (unsigned short*)(ws + 59 * MB);   // 8 MB
  unsigned short* UTb = (unsigned short*)(ws + 67 * MB);  // 32 MB; later P1
  unsigned short* S0T = (unsigned short*)(ws + 99 * MB);  // 32 MB
  float* Pp0 = Olocal;            // alias: Olocal dead after chunkC
  float* Pp1 = (float*)(ws + 67 * MB);  // alias: UTb dead after chainB
  if (ws_size < 131 * MB) return;

  dim3 tb(32, 8), tg(32, 32, 4);
  transpose_all_kernel<<<tg, tb, 0, stream>>>(Wq, Wk, Wv, Wo, Wqkvt, Wto);
  pack_wbm_kernel<<<160, 256, 0, stream>>>(Wb, Wm, Wtf);

  rw8_kernel<<<512, 256, 0, stream>>>(x, Wtf, bb, bm, base_logit, Rf, Wsf, Xb);
  decay2_kernel<<<256, 256, 0, stream>>>(Rf, Wsf, mask, WAf, IAf, DUf, ACf);

  dim3 gqkv(24, 32);
  gemm_pipe_kernel<0><<<gqkv, 256, 0, stream>>>(Xb, Wqkvt, Qb, Kb, Vb, nullptr, nullptr);

  chunkA_kernel<<<256, 512, 0, stream>>>(Qb, Kb, Vb, WAf, IAf, DUf, Olocal, UTb);
  chainB_kernel<<<4096, 256, 0, stream>>>(UTb, ACf, S0T);
  chunkC_kernel<<<256, 512, 0, stream>>>(Qb, S0T, WAf, Olocal, Ob);

  dim3 gwo(8, 32, 2);
  gemm_pipe_kernel<1><<<gwo, 256, 0, stream>>>(Ob, Wto, nullptr, nullptr, nullptr, Pp0, Pp1);

  ln_kernel<<<4096, 256, 0, stream>>>(Pp0, Pp1, bo, x, ln_g, ln_b, (float*)d_out);
}